// Round 1
// baseline (566.243 us; speedup 1.0000x reference)
//
#include <hip/hip_runtime.h>
#include <stdint.h>

// Problem constants (fixed by setup_inputs)
#define B_ 4
#define L_ 4096
#define DM 1024
#define H_ 16
#define D_ 64
#define BH (B_*H_)      // 64
#define N_ (B_*L_)      // 16384
#define CS 128          // chunk size
#define NC (L_/CS)      // 32
#define EPSF 1e-6f

typedef unsigned short u16;
typedef unsigned int   u32;
typedef __attribute__((ext_vector_type(8))) short s16x8;
typedef __attribute__((ext_vector_type(4))) float f32x4;

__device__ __forceinline__ float bf2f(u16 u){
  union { u32 i; float f; } v; v.i = ((u32)u) << 16; return v.f;
}
__device__ __forceinline__ u16 f2bf(float f){
  union { float f; u32 i; } v; v.f = f;
  u32 i = v.i;
  return (u16)((i + 0x7fffu + ((i >> 16) & 1u)) >> 16);  // RNE
}
__device__ __forceinline__ void gload16(const void* g, void* l){
  __builtin_amdgcn_global_load_lds(
      (const __attribute__((address_space(1))) u32*)g,
      (__attribute__((address_space(3))) u32*)l, 16, 0, 0);
}
__device__ __forceinline__ f32x4 mfma16(s16x8 a, s16x8 b, f32x4 c){
  return __builtin_amdgcn_mfma_f32_16x16x32_bf16(a, b, c, 0, 0, 0);
}
__device__ __forceinline__ float sigmoidf_(float x){ return 1.0f/(1.0f+__expf(-x)); }

// ---------------- fp32 -> bf16 convert ----------------
__global__ void cvt_kernel(const float* __restrict__ in, u16* __restrict__ out, int n4){
  int i = blockIdx.x * blockDim.x + threadIdx.x;
  if (i >= n4) return;
  float4 v = ((const float4*)in)[i];
  union { u16 s[4]; uint2 u; } o;
  o.s[0]=f2bf(v.x); o.s[1]=f2bf(v.y); o.s[2]=f2bf(v.z); o.s[3]=f2bf(v.w);
  ((uint2*)out)[i] = o.u;
}

// ---------------- W [K][N] fp32 -> WT [N][K] bf16 ----------------
__global__ __launch_bounds__(256) void transpose_w_kernel(const float* __restrict__ W, u16* __restrict__ WT){
  __shared__ float t[64][65];
  int n0 = blockIdx.x * 64, k0 = blockIdx.y * 64;
  int tx = threadIdx.x & 63, ty = threadIdx.x >> 6;
  #pragma unroll
  for (int s = 0; s < 64; s += 4)
    t[ty + s][tx] = W[(size_t)(k0 + ty + s) * DM + n0 + tx];
  __syncthreads();
  #pragma unroll
  for (int s = 0; s < 64; s += 4)
    WT[(size_t)(n0 + ty + s) * DM + k0 + tx] = f2bf(t[tx][ty + s]);
}

// ---------------- bf16 MFMA GEMM: C[M][Ncols] = A[M][K] * BT[Ncols][K]^T + bias ----------------
// m97 structure: 128x128 tile, BK=32, 4 waves (2x2), global_load_lds staging.
template<int SIGMOID, int OUTF32>
__global__ __launch_bounds__(256) void gemm_kernel(
    const u16* __restrict__ A, const u16* __restrict__ BT,
    const float* __restrict__ bias, u16* __restrict__ outb,
    float* __restrict__ outf, int M, int Ncols, int K)
{
  __shared__ __align__(16) u16 As[128*32];
  __shared__ __align__(16) u16 Bs[128*32];
  int tid = threadIdx.x;
  int wave = tid >> 6, lane = tid & 63;
  int m0 = blockIdx.x * 128, n0 = blockIdx.y * 128;
  int srow = tid >> 2;            // 0..63
  int scol = (tid & 3) * 8;       // 0,8,16,24
  const u16* aptr0 = A + (size_t)(m0 + srow) * K + scol;
  const u16* aptr1 = A + (size_t)(m0 + 64 + srow) * K + scol;
  const u16* bptr0 = BT + (size_t)(n0 + srow) * K + scol;
  const u16* bptr1 = BT + (size_t)(n0 + 64 + srow) * K + scol;
  u16* asd0 = &As[tid * 8]; u16* asd1 = &As[2048 + tid * 8];
  u16* bsd0 = &Bs[tid * 8]; u16* bsd1 = &Bs[2048 + tid * 8];
  f32x4 acc[4][4];
  #pragma unroll
  for (int i=0;i<4;i++)
    #pragma unroll
    for (int j=0;j<4;j++) acc[i][j] = (f32x4){0.f,0.f,0.f,0.f};
  int wr = wave >> 1, wc = wave & 1;
  int fr = lane & 15, kg = (lane >> 4) * 8;
  for (int kb = 0; kb < K; kb += 32){
    __syncthreads();
    gload16(aptr0, asd0); gload16(aptr1, asd1);
    gload16(bptr0, bsd0); gload16(bptr1, bsd1);
    aptr0 += 32; aptr1 += 32; bptr0 += 32; bptr1 += 32;
    __syncthreads();
    s16x8 af[4], bfr[4];
    #pragma unroll
    for (int mi=0;mi<4;mi++) af[mi]  = *(const s16x8*)&As[(wr*64 + mi*16 + fr)*32 + kg];
    #pragma unroll
    for (int ni=0;ni<4;ni++) bfr[ni] = *(const s16x8*)&Bs[(wc*64 + ni*16 + fr)*32 + kg];
    #pragma unroll
    for (int mi=0;mi<4;mi++)
      #pragma unroll
      for (int ni=0;ni<4;ni++)
        acc[mi][ni] = mfma16(af[mi], bfr[ni], acc[mi][ni]);
  }
  #pragma unroll
  for (int mi=0;mi<4;mi++){
    int row = m0 + wr*64 + mi*16 + (lane>>4)*4;
    #pragma unroll
    for (int ni=0;ni<4;ni++){
      int col = n0 + wc*64 + ni*16 + fr;
      float bv = bias[col];
      #pragma unroll
      for (int r=0;r<4;r++){
        float val = acc[mi][ni][r] + bv;
        if (SIGMOID) val = sigmoidf_(val);
        if (OUTF32) outf[(size_t)(row + r) * Ncols + col] = val;
        else        outb[(size_t)(row + r) * Ncols + col] = f2bf(val);
      }
    }
  }
}

// ---------------- per-chunk sums of q,k over l ----------------
__global__ __launch_bounds__(64) void chunk_sums_kernel(
    const u16* __restrict__ q, const u16* __restrict__ k,
    float* __restrict__ sumQ, float* __restrict__ sumK){
  int bhc = blockIdx.x; int bh = bhc >> 5, c = bhc & 31;
  int b = bh >> 4, h = bh & 15;
  int d = threadIdx.x;
  size_t base = ((size_t)(b * L_ + c * CS)) * DM + h * D_ + d;
  float sq = 0.f, sk = 0.f;
  for (int i = 0; i < CS; i++){
    sq += bf2f(q[base + (size_t)i * DM]);
    sk += bf2f(k[base + (size_t)i * DM]);
  }
  sumQ[bhc * D_ + d] = sq;
  sumK[bhc * D_ + d] = sk;
}

// ---------------- exclusive scan over chunk axis (2 arrays, in place) ----------------
__global__ __launch_bounds__(64) void scan2_kernel(float* __restrict__ A, float* __restrict__ Bv){
  int bh = blockIdx.x, d = threadIdx.x;
  float ra = 0.f, rb = 0.f;
  for (int c = 0; c < NC; c++){
    int o = (bh * NC + c) * D_ + d;
    float ta = A[o], tb = Bv[o];
    A[o] = ra; Bv[o] = rb;
    ra += ta; rb += tb;
  }
}

// ---------------- sink_incoming, source_outgoing ----------------
__global__ __launch_bounds__(64) void si_so_kernel(
    const u16* __restrict__ q, const u16* __restrict__ k,
    const float* __restrict__ sumQx, const float* __restrict__ sumKx,
    float* __restrict__ si, float* __restrict__ so){
  int bhc = blockIdx.x; int bh = bhc >> 5, c = bhc & 31;
  int b = bh >> 4, h = bh & 15;
  int d = threadIdx.x;
  float runQ = sumQx[bhc * D_ + d];
  float runK = sumKx[bhc * D_ + d];
  size_t base = ((size_t)(b * L_ + c * CS)) * DM + h * D_ + d;
  size_t lb = (size_t)bh * L_ + c * CS;
  for (int i = 0; i < CS; i++){
    float qv = bf2f(q[base + (size_t)i * DM]);
    float kv = bf2f(k[base + (size_t)i * DM]);
    runQ += qv; runK += kv;
    float a  = (qv + EPSF) * (runK + EPSF);
    float bb = (kv + EPSF) * (runQ + EPSF);
    #pragma unroll
    for (int off = 32; off > 0; off >>= 1){
      a  += __shfl_xor(a, off);
      bb += __shfl_xor(bb, off);
    }
    if (d == 0){
      float n = (float)(c * CS + i + 1);
      si[lb + i] = n / a;
      so[lb + i] = n / bb;
    }
  }
}

// ---------------- per-chunk sums of q*si, k*so ----------------
__global__ __launch_bounds__(64) void chunk_sums_mod_kernel(
    const u16* __restrict__ q, const u16* __restrict__ k,
    const float* __restrict__ si, const float* __restrict__ so,
    float* __restrict__ sumQsi, float* __restrict__ sumKso){
  int bhc = blockIdx.x; int bh = bhc >> 5, c = bhc & 31;
  int b = bh >> 4, h = bh & 15;
  int d = threadIdx.x;
  size_t base = ((size_t)(b * L_ + c * CS)) * DM + h * D_ + d;
  size_t lb = (size_t)bh * L_ + c * CS;
  float sq = 0.f, sk = 0.f;
  for (int i = 0; i < CS; i++){
    sq += bf2f(q[base + (size_t)i * DM]) * si[lb + i];
    sk += bf2f(k[base + (size_t)i * DM]) * so[lb + i];
  }
  sumQsi[bhc * D_ + d] = sq;
  sumKso[bhc * D_ + d] = sk;
}

// ---------------- conserved_sink -> sink_allocation, conserved_source ----------------
__global__ __launch_bounds__(64) void cons_kernel(
    const u16* __restrict__ q, const u16* __restrict__ k,
    const float* __restrict__ si, const float* __restrict__ so,
    const float* __restrict__ sumQsiX, const float* __restrict__ sumKsoX,
    float* __restrict__ csource, float* __restrict__ salloc){
  int bhc = blockIdx.x; int bh = bhc >> 5, c = bhc & 31;
  int b = bh >> 4, h = bh & 15;
  int d = threadIdx.x;
  float runQsi = sumQsiX[bhc * D_ + d];
  float runKso = sumKsoX[bhc * D_ + d];
  size_t base = ((size_t)(b * L_ + c * CS)) * DM + h * D_ + d;
  size_t lb = (size_t)bh * L_ + c * CS;
  for (int i = 0; i < CS; i++){
    float qv = bf2f(q[base + (size_t)i * DM]);
    float kv = bf2f(k[base + (size_t)i * DM]);
    runQsi += qv * si[lb + i];
    runKso += kv * so[lb + i];
    float a  = (qv + EPSF) * (runKso + EPSF);   // conserved_sink terms
    float bb = (kv + EPSF) * (runQsi + EPSF);   // conserved_source terms
    #pragma unroll
    for (int off = 32; off > 0; off >>= 1){
      a  += __shfl_xor(a, off);
      bb += __shfl_xor(bb, off);
    }
    if (d == 0){
      float inv = 1.0f / (float)(c * CS + i + 1);
      salloc[lb + i]  = sigmoidf_(a * inv);
      csource[lb + i] = bb * inv;
    }
  }
}

// ---------------- exp(csource) chunk sums + exclusive scan ----------------
__global__ __launch_bounds__(64) void cs_off_kernel(const float* __restrict__ csource, float* __restrict__ csOff){
  int bh = blockIdx.x; int lane = threadIdx.x;
  float s = 0.f;
  if (lane < NC){
    size_t base = (size_t)bh * L_ + (size_t)lane * CS;
    for (int i = 0; i < CS; i++) s += __expf(csource[base + i]);
  }
  float run = s;
  #pragma unroll
  for (int off = 1; off < 32; off <<= 1){
    float t = __shfl_up(run, off);
    if (lane >= off) run += t;
  }
  if (lane < NC) csOff[bh * NC + lane] = run - s;  // exclusive
}

// ---------------- source_competition ----------------
__global__ __launch_bounds__(64) void scomp_kernel(
    const float* __restrict__ csource, const float* __restrict__ csOff,
    float* __restrict__ scomp){
  int bhc = blockIdx.x; int bh = bhc >> 5, c = bhc & 31;
  int lane = threadIdx.x;
  float off = csOff[bh * NC + c];
  size_t base = (size_t)bh * L_ + c * CS;
  #pragma unroll
  for (int half = 0; half < 2; half++){
    int i = half * 64 + lane;
    float cs = __expf(csource[base + i]);
    float run = cs;
    #pragma unroll
    for (int o = 1; o < 64; o <<= 1){
      float t = __shfl_up(run, o);
      if (lane >= o) run += t;
    }
    scomp[base + i] = cs / (off + run) * (float)(c * CS + i + 1);
    off += __shfl(run, 63);
  }
}

// ---------------- per-chunk VK sums: VK[m][d] = sum_l v[l][m]*scomp[l]*k[l][d] ----------------
__global__ __launch_bounds__(256) void vk_chunk_kernel(
    const u16* __restrict__ k, const u16* __restrict__ v,
    const float* __restrict__ scomp, float* __restrict__ vkc){
  __shared__ float ks[32][64];
  __shared__ float vs[32][64];
  int bhc = blockIdx.x; int bh = bhc >> 5, c = bhc & 31;
  int b = bh >> 4, h = bh & 15;
  int tid = threadIdx.x;
  int m = tid >> 2, d0 = (tid & 3) * 16;
  float acc[16];
  #pragma unroll
  for (int j = 0; j < 16; j++) acc[j] = 0.f;
  size_t gbase = ((size_t)(b * L_ + c * CS)) * DM + h * D_;
  size_t sbase = (size_t)bh * L_ + c * CS;
  int r = tid >> 3, cc = (tid & 7) * 8;
  for (int s0 = 0; s0 < CS; s0 += 32){
    __syncthreads();
    float sc = scomp[sbase + s0 + r];
    uint4 ku = *(const uint4*)(k + gbase + (size_t)(s0 + r) * DM + cc);
    uint4 vu = *(const uint4*)(v + gbase + (size_t)(s0 + r) * DM + cc);
    const u16* kp = (const u16*)&ku; const u16* vp = (const u16*)&vu;
    #pragma unroll
    for (int j = 0; j < 8; j++){
      ks[r][cc + j] = bf2f(kp[j]);
      vs[r][cc + j] = bf2f(vp[j]) * sc;
    }
    __syncthreads();
    #pragma unroll
    for (int i = 0; i < 32; i++){
      float vm = vs[i][m];
      #pragma unroll
      for (int j4 = 0; j4 < 4; j4++){
        float4 kk = *(const float4*)&ks[i][d0 + j4*4];
        acc[j4*4+0] += vm * kk.x; acc[j4*4+1] += vm * kk.y;
        acc[j4*4+2] += vm * kk.z; acc[j4*4+3] += vm * kk.w;
      }
    }
  }
  float* outp = vkc + (size_t)bhc * (D_*D_) + m * D_ + d0;
  #pragma unroll
  for (int j = 0; j < 16; j++) outp[j] = acc[j];
}

// ---------------- exclusive scan of VK over chunks (in place) ----------------
__global__ __launch_bounds__(256) void vk_scan_kernel(float* __restrict__ vkc){
  int idx = blockIdx.x * 256 + threadIdx.x;   // over BH*4096
  int bh = idx >> 12;
  int e  = idx & 4095;
  size_t base = ((size_t)bh * NC) * 4096 + e;
  float run = 0.f;
  for (int c = 0; c < NC; c++){
    size_t o = base + (size_t)c * 4096;
    float t = vkc[o]; vkc[o] = run; run += t;
  }
}

// ---------------- causal attention per (bh, chunk) ----------------
__global__ __launch_bounds__(256) void attn_kernel(
    const u16* __restrict__ q, const u16* __restrict__ k, const u16* __restrict__ v,
    const float* __restrict__ si, const float* __restrict__ scomp, const float* __restrict__ salloc,
    const float* __restrict__ vkc, u16* __restrict__ attnout)
{
  __shared__ __align__(16) u16 qs[128*64];    // qmod rows [l][d]
  __shared__ __align__(16) u16 ks2[128*64];   // k rows    [j][d]
  __shared__ __align__(16) u16 vts[64*128];   // (v*scomp)^T [m][j]
  __shared__ __align__(16) u16 vks[64*64];    // VKprev [m][d]
  __shared__ __align__(16) u16 ss[128*32];    // masked S strip [l][j-in-32]
  int bhc = blockIdx.x; int bh = bhc >> 5, c = bhc & 31;
  int b = bh >> 4, h = bh & 15;
  int tid = threadIdx.x, wave = tid >> 6, lane = tid & 63;
  size_t gbase = ((size_t)(b * L_ + c * CS)) * DM + h * D_;
  size_t sbase = (size_t)bh * L_ + c * CS;
  // staging
  {
    int r = tid >> 1;
    int cc = (tid & 1) * 32;
    int l = c * CS + r;
    float qscale = si[sbase + r] / (float)(l + 1);
    float vscale = scomp[sbase + r];
    #pragma unroll
    for (int j = 0; j < 4; j++){
      uint4 qu = *(const uint4*)(q + gbase + (size_t)r * DM + cc + j*8);
      uint4 kuv = *(const uint4*)(k + gbase + (size_t)r * DM + cc + j*8);
      uint4 vu = *(const uint4*)(v + gbase + (size_t)r * DM + cc + j*8);
      const u16* qp = (const u16*)&qu; const u16* vp = (const u16*)&vu;
      u16 tmp[8];
      #pragma unroll
      for (int e = 0; e < 8; e++) tmp[e] = f2bf(bf2f(qp[e]) * qscale);
      *(uint4*)&qs[r*64 + cc + j*8] = *(uint4*)tmp;
      *(uint4*)&ks2[r*64 + cc + j*8] = kuv;
      #pragma unroll
      for (int e = 0; e < 8; e++) vts[(cc + j*8 + e)*128 + r] = f2bf(bf2f(vp[e]) * vscale);
    }
    const float* vkp = vkc + (size_t)bhc * (D_*D_) + tid * 16;
    u16 tv[16];
    #pragma unroll
    for (int e = 0; e < 16; e++) tv[e] = f2bf(vkp[e]);
    *(uint4*)&vks[tid*16]   = *(uint4*)&tv[0];
    *(uint4*)&vks[tid*16+8] = *(uint4*)&tv[8];
  }
  __syncthreads();
  int t0 = wave, t1 = 7 - wave;   // balanced l-tile pair per wave
  int fr = lane & 15, kg = (lane >> 4) * 8;
  f32x4 acc[2][4];
  #pragma unroll
  for (int i=0;i<2;i++)
    #pragma unroll
    for (int j=0;j<4;j++) acc[i][j] = (f32x4){0.f,0.f,0.f,0.f};
  s16x8 aq[2][2];
  #pragma unroll
  for (int ti = 0; ti < 2; ti++){
    int t = ti ? t1 : t0;
    #pragma unroll
    for (int kk = 0; kk < 2; kk++)
      aq[ti][kk] = *(const s16x8*)&qs[(t*16 + fr)*64 + kk*32 + kg];
  }
  // inter-chunk: qmod @ VKprev^T
  #pragma unroll
  for (int mt = 0; mt < 4; mt++){
    #pragma unroll
    for (int kk = 0; kk < 2; kk++){
      s16x8 bv = *(const s16x8*)&vks[(mt*16 + fr)*64 + kk*32 + kg];
      acc[0][mt] = mfma16(aq[0][kk], bv, acc[0][mt]);
      acc[1][mt] = mfma16(aq[1][kk], bv, acc[1][mt]);
    }
  }
  // intra-chunk, 32-j strips
  for (int jt = 0; jt < 4; jt++){
    __syncthreads();
    #pragma unroll
    for (int ti = 0; ti < 2; ti++){
      int t = ti ? t1 : t0;
      #pragma unroll
      for (int u = 0; u < 2; u++){
        int jj = jt*2 + u;
        f32x4 sacc = (f32x4){0.f,0.f,0.f,0.f};
        if (jj <= t){
          #pragma unroll
          for (int kk = 0; kk < 2; kk++){
            s16x8 bkf = *(const s16x8*)&ks2[(jj*16 + fr)*64 + kk*32 + kg];
            sacc = mfma16(aq[ti][kk], bkf, sacc);
          }
        }
        int lrow = t*16 + (lane>>4)*4;
        int jcol = jj*16 + fr;
        #pragma unroll
        for (int r = 0; r < 4; r++){
          float sv = (jcol <= lrow + r) ? sacc[r] : 0.f;
          ss[(lrow + r)*32 + u*16 + fr] = f2bf(sv);
        }
      }
    }
    __syncthreads();
    #pragma unroll
    for (int ti = 0; ti < 2; ti++){
      int t = ti ? t1 : t0;
      if (jt*32 <= t*16 + 15){
        s16x8 as = *(const s16x8*)&ss[(t*16 + fr)*32 + kg];
        #pragma unroll
        for (int mt = 0; mt < 4; mt++){
          s16x8 bvv = *(const s16x8*)&vts[(mt*16 + fr)*128 + jt*32 + kg];
          acc[ti][mt] = mfma16(as, bvv, acc[ti][mt]);
        }
      }
    }
  }
  // epilogue: * sink_allocation, write bf16 [B,L,DM]
  #pragma unroll
  for (int ti = 0; ti < 2; ti++){
    int t = ti ? t1 : t0;
    int lrow = t*16 + (lane>>4)*4;
    #pragma unroll
    for (int r = 0; r < 4; r++){
      float sa = salloc[sbase + lrow + r];
      size_t orow = ((size_t)(b * L_ + c * CS + lrow + r)) * DM + h * D_;
      #pragma unroll
      for (int mt = 0; mt < 4; mt++){
        attnout[orow + mt*16 + fr] = f2bf(acc[ti][mt][r] * sa);
      }
    }
  }
}

extern "C" void kernel_launch(void* const* d_in, const int* in_sizes, int n_in,
                              void* d_out, int out_size, void* d_ws, size_t ws_size,
                              hipStream_t stream){
  (void)in_sizes; (void)n_in; (void)out_size; (void)ws_size;
  const float* x  = (const float*)d_in[0];
  const float* Wq = (const float*)d_in[1];
  const float* bq = (const float*)d_in[2];
  const float* Wk = (const float*)d_in[3];
  const float* bk = (const float*)d_in[4];
  const float* Wv = (const float*)d_in[5];
  const float* bv = (const float*)d_in[6];
  const float* Wo = (const float*)d_in[7];
  const float* bo = (const float*)d_in[8];

  char* p = (char*)d_ws;
  auto carve = [&](size_t bytes) -> void* {
    void* r = (void*)p; p += (bytes + 255) & ~(size_t)255; return r;
  };
  u16* xb  = (u16*)carve((size_t)N_*DM*2);
  u16* wqT = (u16*)carve((size_t)DM*DM*2);
  u16* wkT = (u16*)carve((size_t)DM*DM*2);
  u16* wvT = (u16*)carve((size_t)DM*DM*2);
  u16* woT = (u16*)carve((size_t)DM*DM*2);
  u16* qb  = (u16*)carve((size_t)N_*DM*2);
  u16* kb  = (u16*)carve((size_t)N_*DM*2);
  u16* vb  = (u16*)carve((size_t)N_*DM*2);
  u16* ao  = (u16*)carve((size_t)N_*DM*2);
  float* si   = (float*)carve((size_t)BH*L_*4);
  float* so   = (float*)carve((size_t)BH*L_*4);
  float* csrc = (float*)carve((size_t)BH*L_*4);
  float* sall = (float*)carve((size_t)BH*L_*4);
  float* scmp = (float*)carve((size_t)BH*L_*4);
  float* sumQ   = (float*)carve((size_t)BH*NC*D_*4);
  float* sumK   = (float*)carve((size_t)BH*NC*D_*4);
  float* sumQsi = (float*)carve((size_t)BH*NC*D_*4);
  float* sumKso = (float*)carve((size_t)BH*NC*D_*4);
  float* csOff  = (float*)carve((size_t)BH*NC*4);
  float* vkc    = (float*)carve((size_t)BH*NC*(size_t)(D_*D_)*4);

  // 1. conversions
  cvt_kernel<<<(N_*DM/4 + 255)/256, 256, 0, stream>>>(x, xb, N_*DM/4);
  dim3 tg(DM/64, DM/64);
  transpose_w_kernel<<<tg, 256, 0, stream>>>(Wq, wqT);
  transpose_w_kernel<<<tg, 256, 0, stream>>>(Wk, wkT);
  transpose_w_kernel<<<tg, 256, 0, stream>>>(Wv, wvT);
  transpose_w_kernel<<<tg, 256, 0, stream>>>(Wo, woT);
  // 2. projections
  dim3 gg(N_/128, DM/128);
  gemm_kernel<1,0><<<gg, 256, 0, stream>>>(xb, wqT, bq, qb, nullptr, N_, DM, DM);
  gemm_kernel<1,0><<<gg, 256, 0, stream>>>(xb, wkT, bk, kb, nullptr, N_, DM, DM);
  gemm_kernel<0,0><<<gg, 256, 0, stream>>>(xb, wvT, bv, vb, nullptr, N_, DM, DM);
  // 3. normalizer scans
  chunk_sums_kernel<<<BH*NC, 64, 0, stream>>>(qb, kb, sumQ, sumK);
  scan2_kernel<<<BH, 64, 0, stream>>>(sumQ, sumK);
  si_so_kernel<<<BH*NC, 64, 0, stream>>>(qb, kb, sumQ, sumK, si, so);
  chunk_sums_mod_kernel<<<BH*NC, 64, 0, stream>>>(qb, kb, si, so, sumQsi, sumKso);
  scan2_kernel<<<BH, 64, 0, stream>>>(sumQsi, sumKso);
  cons_kernel<<<BH*NC, 64, 0, stream>>>(qb, kb, si, so, sumQsi, sumKso, csrc, sall);
  cs_off_kernel<<<BH, 64, 0, stream>>>(csrc, csOff);
  scomp_kernel<<<BH*NC, 64, 0, stream>>>(csrc, csOff, scmp);
  // 4. causal linear attention
  vk_chunk_kernel<<<BH*NC, 256, 0, stream>>>(kb, vb, scmp, vkc);
  vk_scan_kernel<<<(BH*D_*D_)/256, 256, 0, stream>>>(vkc);
  attn_kernel<<<BH*NC, 256, 0, stream>>>(qb, kb, vb, si, scmp, sall, vkc, ao);
  // 5. output projection
  gemm_kernel<0,1><<<gg, 256, 0, stream>>>(ao, woT, bo, nullptr, (float*)d_out, N_, DM, DM);
}

// Round 2
// 464.495 us; speedup vs baseline: 1.2191x; 1.2191x over previous
//
#include <hip/hip_runtime.h>
#include <stdint.h>

// Problem constants (fixed by setup_inputs)
#define B_ 4
#define L_ 4096
#define DM 1024
#define H_ 16
#define D_ 64
#define BH (B_*H_)      // 64
#define N_ (B_*L_)      // 16384
#define CS 128          // chunk size for causal attention
#define NC (L_/CS)      // 32
#define SC 64           // chunk size for normalizer scans
#define NSC (L_/SC)     // 64
#define EPSF 1e-6f

typedef unsigned short u16;
typedef unsigned int   u32;
typedef __attribute__((ext_vector_type(8))) short s16x8;
typedef __attribute__((ext_vector_type(4))) float f32x4;

__device__ __forceinline__ float bf2f(u16 u){
  union { u32 i; float f; } v; v.i = ((u32)u) << 16; return v.f;
}
__device__ __forceinline__ u16 f2bf(float f){
  union { float f; u32 i; } v; v.f = f;
  u32 i = v.i;
  return (u16)((i + 0x7fffu + ((i >> 16) & 1u)) >> 16);  // RNE
}
__device__ __forceinline__ void gload16(const void* g, void* l){
  __builtin_amdgcn_global_load_lds(
      (const __attribute__((address_space(1))) u32*)g,
      (__attribute__((address_space(3))) u32*)l, 16, 0, 0);
}
__device__ __forceinline__ f32x4 mfma16(s16x8 a, s16x8 b, f32x4 c){
  return __builtin_amdgcn_mfma_f32_16x16x32_bf16(a, b, c, 0, 0, 0);
}
__device__ __forceinline__ float sigmoidf_(float x){ return 1.0f/(1.0f+__expf(-x)); }

// ---------------- fp32 -> bf16 convert ----------------
__global__ void cvt_kernel(const float* __restrict__ in, u16* __restrict__ out, int n4){
  int i = blockIdx.x * blockDim.x + threadIdx.x;
  if (i >= n4) return;
  float4 v = ((const float4*)in)[i];
  union { u16 s[4]; uint2 u; } o;
  o.s[0]=f2bf(v.x); o.s[1]=f2bf(v.y); o.s[2]=f2bf(v.z); o.s[3]=f2bf(v.w);
  ((uint2*)out)[i] = o.u;
}

// ---------------- W [K][N] fp32 -> WT [N][K] bf16 ----------------
__global__ __launch_bounds__(256) void transpose_w_kernel(const float* __restrict__ W, u16* __restrict__ WT){
  __shared__ float t[64][65];
  int n0 = blockIdx.x * 64, k0 = blockIdx.y * 64;
  int tx = threadIdx.x & 63, ty = threadIdx.x >> 6;
  #pragma unroll
  for (int s = 0; s < 64; s += 4)
    t[ty + s][tx] = W[(size_t)(k0 + ty + s) * DM + n0 + tx];
  __syncthreads();
  #pragma unroll
  for (int s = 0; s < 64; s += 4)
    WT[(size_t)(n0 + ty + s) * DM + k0 + tx] = f2bf(t[tx][ty + s]);
}

// ---------------- bf16 MFMA GEMM: C[M][Ncols] = A[M][K] * BT[Ncols][K]^T + bias ----------------
// m97 structure: 128x128 tile, BK=32, 4 waves (2x2), global_load_lds staging.
// SUMS: also emit per-64-row column sums (post-activation) -> sums[(bh*NSC+sc)*64+d]
template<int SIGMOID, int OUTF32, int SUMS>
__global__ __launch_bounds__(256) void gemm_kernel(
    const u16* __restrict__ A, const u16* __restrict__ BT,
    const float* __restrict__ bias, u16* __restrict__ outb,
    float* __restrict__ outf, float* __restrict__ sums,
    int M, int Ncols, int K)
{
  __shared__ __align__(16) u16 As[128*32];
  __shared__ __align__(16) u16 Bs[128*32];
  int tid = threadIdx.x;
  int wave = tid >> 6, lane = tid & 63;
  int m0 = blockIdx.x * 128, n0 = blockIdx.y * 128;
  int srow = tid >> 2;            // 0..63
  int scol = (tid & 3) * 8;       // 0,8,16,24
  const u16* aptr0 = A + (size_t)(m0 + srow) * K + scol;
  const u16* aptr1 = A + (size_t)(m0 + 64 + srow) * K + scol;
  const u16* bptr0 = BT + (size_t)(n0 + srow) * K + scol;
  const u16* bptr1 = BT + (size_t)(n0 + 64 + srow) * K + scol;
  u16* asd0 = &As[tid * 8]; u16* asd1 = &As[2048 + tid * 8];
  u16* bsd0 = &Bs[tid * 8]; u16* bsd1 = &Bs[2048 + tid * 8];
  f32x4 acc[4][4];
  #pragma unroll
  for (int i=0;i<4;i++)
    #pragma unroll
    for (int j=0;j<4;j++) acc[i][j] = (f32x4){0.f,0.f,0.f,0.f};
  int wr = wave >> 1, wc = wave & 1;
  int fr = lane & 15, kg = (lane >> 4) * 8;
  for (int kb = 0; kb < K; kb += 32){
    __syncthreads();
    gload16(aptr0, asd0); gload16(aptr1, asd1);
    gload16(bptr0, bsd0); gload16(bptr1, bsd1);
    aptr0 += 32; aptr1 += 32; bptr0 += 32; bptr1 += 32;
    __syncthreads();
    s16x8 af[4], bfr[4];
    #pragma unroll
    for (int mi=0;mi<4;mi++) af[mi]  = *(const s16x8*)&As[(wr*64 + mi*16 + fr)*32 + kg];
    #pragma unroll
    for (int ni=0;ni<4;ni++) bfr[ni] = *(const s16x8*)&Bs[(wc*64 + ni*16 + fr)*32 + kg];
    #pragma unroll
    for (int mi=0;mi<4;mi++)
      #pragma unroll
      for (int ni=0;ni<4;ni++)
        acc[mi][ni] = mfma16(af[mi], bfr[ni], acc[mi][ni]);
  }
  float csum[4] = {0.f,0.f,0.f,0.f};
  #pragma unroll
  for (int mi=0;mi<4;mi++){
    int row = m0 + wr*64 + mi*16 + (lane>>4)*4;
    #pragma unroll
    for (int ni=0;ni<4;ni++){
      int col = n0 + wc*64 + ni*16 + fr;
      float bv = bias[col];
      #pragma unroll
      for (int r=0;r<4;r++){
        float val = acc[mi][ni][r] + bv;
        if (SIGMOID) val = sigmoidf_(val);
        if (OUTF32) outf[(size_t)(row + r) * Ncols + col] = val;
        else        outb[(size_t)(row + r) * Ncols + col] = f2bf(val);
        if (SUMS) csum[ni] += val;
      }
    }
  }
  if (SUMS){
    int bb  = m0 >> 12;                 // row block -> batch (L_=4096)
    int scl = ((m0 & 4095) >> 6) + wr;  // scan-chunk within batch
    int hh  = (n0 >> 6) + wc;           // head
    int bh  = bb * H_ + hh;
    #pragma unroll
    for (int ni=0;ni<4;ni++){
      float s = csum[ni];
      s += __shfl_xor(s, 16);
      s += __shfl_xor(s, 32);
      if (lane < 16) sums[((size_t)bh*NSC + scl)*64 + ni*16 + fr] = s;
    }
  }
}

// ---------------- exclusive scan over scan-chunk axis (2 arrays, in place) ----------------
__global__ __launch_bounds__(64) void scan2_kernel(float* __restrict__ A, float* __restrict__ Bv){
  int bh = blockIdx.x, d = threadIdx.x;
  float ra = 0.f, rb = 0.f;
  for (int c = 0; c < NSC; c++){
    size_t o = ((size_t)bh * NSC + c) * 64 + d;
    float ta = A[o], tb = Bv[o];
    A[o] = ra; Bv[o] = rb;
    ra += ta; rb += tb;
  }
}

// ---------------- fused sink_incoming/source_outgoing + mod chunk sums ----------------
// block = (bh, sc), 64 threads (1 wave).
// P1: thread=d column cumsums -> swizzled LDS; P2: thread=l dot products; P3: thread=d mod sums.
__global__ __launch_bounds__(64) void siso_fused_kernel(
    const u16* __restrict__ q, const u16* __restrict__ k,
    const float* __restrict__ sumQx, const float* __restrict__ sumKx,
    float* __restrict__ si, float* __restrict__ so,
    float* __restrict__ sumQsi, float* __restrict__ sumKso)
{
  __shared__ float cq[64*64];
  __shared__ float ck[64*64];
  __shared__ float siv[64], sov[64];
  int bhc = blockIdx.x; int bh = bhc >> 6, sc = bhc & 63;
  int b = bh >> 4, h = bh & 15;
  int lane = threadIdx.x;
  size_t gbase = ((size_t)(b*L_ + sc*SC))*DM + h*D_;
  size_t lb = (size_t)bh*L_ + sc*SC;
  // P1: column cumsums of q and k (coalesced row-wise reads)
  {
    float runQ = sumQx[bhc*64 + lane];
    float runK = sumKx[bhc*64 + lane];
    for (int l = 0; l < SC; l++){
      runQ += bf2f(q[gbase + (size_t)l*DM + lane]);
      runK += bf2f(k[gbase + (size_t)l*DM + lane]);
      int sw = lane ^ (l & 31);
      cq[l*64 + sw] = runQ;
      ck[l*64 + sw] = runK;
    }
  }
  __syncthreads();
  // P2: per-position denominators
  {
    int l = lane;
    const u16* qrow = q + gbase + (size_t)l*DM;
    const u16* krow = k + gbase + (size_t)l*DM;
    uint4 qr[8], kr[8];
    #pragma unroll
    for (int j=0;j<8;j++){ qr[j]=((const uint4*)qrow)[j]; kr[j]=((const uint4*)krow)[j]; }
    const u16* qp = (const u16*)qr; const u16* kp = (const u16*)kr;
    float a = 0.f, b2 = 0.f;
    #pragma unroll
    for (int d = 0; d < 64; d++){
      int sw = d ^ (l & 31);
      a  += (bf2f(qp[d])+EPSF) * (ck[l*64+sw]+EPSF);
      b2 += (bf2f(kp[d])+EPSF) * (cq[l*64+sw]+EPSF);
    }
    float n = (float)(sc*SC + l + 1);
    float vsi = n/a, vso = n/b2;
    si[lb+l] = vsi; so[lb+l] = vso;
    siv[l] = vsi;   sov[l] = vso;
  }
  __syncthreads();
  // P3: per-chunk sums of q*si, k*so (thread=d)
  {
    float sq = 0.f, sk = 0.f;
    for (int l = 0; l < SC; l++){
      sq += bf2f(q[gbase + (size_t)l*DM + lane]) * siv[l];
      sk += bf2f(k[gbase + (size_t)l*DM + lane]) * sov[l];
    }
    sumQsi[bhc*64 + lane] = sq;
    sumKso[bhc*64 + lane] = sk;
  }
}

// ---------------- fused conserved_sink/source -> sall, csrc + exp chunk sums ----------------
__global__ __launch_bounds__(64) void cons_fused_kernel(
    const u16* __restrict__ q, const u16* __restrict__ k,
    const float* __restrict__ si, const float* __restrict__ so,
    const float* __restrict__ sumQsiX, const float* __restrict__ sumKsoX,
    float* __restrict__ csrc, float* __restrict__ sall, float* __restrict__ csSum)
{
  __shared__ float cq[64*64];   // cumsum q*si
  __shared__ float ck[64*64];   // cumsum k*so
  __shared__ float siv[64], sov[64];
  int bhc = blockIdx.x; int bh = bhc >> 6, sc = bhc & 63;
  int b = bh >> 4, h = bh & 15;
  int lane = threadIdx.x;
  size_t gbase = ((size_t)(b*L_ + sc*SC))*DM + h*D_;
  size_t lb = (size_t)bh*L_ + sc*SC;
  siv[lane] = si[lb + lane];
  sov[lane] = so[lb + lane];
  __syncthreads();
  // P1
  {
    float runQ = sumQsiX[bhc*64 + lane];
    float runK = sumKsoX[bhc*64 + lane];
    for (int l = 0; l < SC; l++){
      runQ += bf2f(q[gbase + (size_t)l*DM + lane]) * siv[l];
      runK += bf2f(k[gbase + (size_t)l*DM + lane]) * sov[l];
      int sw = lane ^ (l & 31);
      cq[l*64 + sw] = runQ;
      ck[l*64 + sw] = runK;
    }
  }
  __syncthreads();
  // P2
  {
    int l = lane;
    const u16* qrow = q + gbase + (size_t)l*DM;
    const u16* krow = k + gbase + (size_t)l*DM;
    uint4 qr[8], kr[8];
    #pragma unroll
    for (int j=0;j<8;j++){ qr[j]=((const uint4*)qrow)[j]; kr[j]=((const uint4*)krow)[j]; }
    const u16* qp = (const u16*)qr; const u16* kp = (const u16*)kr;
    float a = 0.f, b2 = 0.f;
    #pragma unroll
    for (int d = 0; d < 64; d++){
      int sw = d ^ (l & 31);
      a  += (bf2f(qp[d])+EPSF) * (ck[l*64+sw]+EPSF);   // conserved_sink
      b2 += (bf2f(kp[d])+EPSF) * (cq[l*64+sw]+EPSF);   // conserved_source
    }
    float inv = 1.0f / (float)(sc*SC + l + 1);
    sall[lb+l] = sigmoidf_(a * inv);
    float cs = b2 * inv;
    csrc[lb+l] = cs;
    float e = __expf(cs);
    #pragma unroll
    for (int off = 32; off > 0; off >>= 1) e += __shfl_xor(e, off);
    if (lane == 0) csSum[bhc] = e;
  }
}

// ---------------- exclusive scan of exp-chunk-sums over NSC chunks ----------------
__global__ __launch_bounds__(64) void cs_scan_kernel(const float* __restrict__ csSum, float* __restrict__ csOff){
  int bh = blockIdx.x; int lane = threadIdx.x;
  float v = csSum[bh * NSC + lane];
  float run = v;
  #pragma unroll
  for (int o = 1; o < 64; o <<= 1){
    float t = __shfl_up(run, o);
    if (lane >= o) run += t;
  }
  csOff[bh * NSC + lane] = run - v;  // exclusive
}

// ---------------- source_competition ----------------
__global__ __launch_bounds__(64) void scomp_kernel(
    const float* __restrict__ csrc, const float* __restrict__ csOff,
    float* __restrict__ scomp){
  int bhc = blockIdx.x; int bh = bhc >> 6, sc = bhc & 63;
  int lane = threadIdx.x;
  size_t idx = (size_t)bh * L_ + sc * SC + lane;
  float cs = __expf(csrc[idx]);
  float run = cs;
  #pragma unroll
  for (int o = 1; o < 64; o <<= 1){
    float t = __shfl_up(run, o);
    if (lane >= o) run += t;
  }
  scomp[idx] = cs / (csOff[bh*NSC + sc] + run) * (float)(sc*SC + lane + 1);
}

// ---------------- per-chunk VK sums: VK[m][d] = sum_l v[l][m]*scomp[l]*k[l][d] ----------------
__global__ __launch_bounds__(256) void vk_chunk_kernel(
    const u16* __restrict__ k, const u16* __restrict__ v,
    const float* __restrict__ scomp, float* __restrict__ vkc){
  __shared__ float ks[32][64];
  __shared__ float vs[32][64];
  int bhc = blockIdx.x; int bh = bhc >> 5, c = bhc & 31;
  int b = bh >> 4, h = bh & 15;
  int tid = threadIdx.x;
  int m = tid >> 2, d0 = (tid & 3) * 16;
  float acc[16];
  #pragma unroll
  for (int j = 0; j < 16; j++) acc[j] = 0.f;
  size_t gbase = ((size_t)(b * L_ + c * CS)) * DM + h * D_;
  size_t sbase = (size_t)bh * L_ + c * CS;
  int r = tid >> 3, cc = (tid & 7) * 8;
  for (int s0 = 0; s0 < CS; s0 += 32){
    __syncthreads();
    float sc = scomp[sbase + s0 + r];
    uint4 ku = *(const uint4*)(k + gbase + (size_t)(s0 + r) * DM + cc);
    uint4 vu = *(const uint4*)(v + gbase + (size_t)(s0 + r) * DM + cc);
    const u16* kp = (const u16*)&ku; const u16* vp = (const u16*)&vu;
    #pragma unroll
    for (int j = 0; j < 8; j++){
      ks[r][cc + j] = bf2f(kp[j]);
      vs[r][cc + j] = bf2f(vp[j]) * sc;
    }
    __syncthreads();
    #pragma unroll
    for (int i = 0; i < 32; i++){
      float vm = vs[i][m];
      #pragma unroll
      for (int j4 = 0; j4 < 4; j4++){
        float4 kk = *(const float4*)&ks[i][d0 + j4*4];
        acc[j4*4+0] += vm * kk.x; acc[j4*4+1] += vm * kk.y;
        acc[j4*4+2] += vm * kk.z; acc[j4*4+3] += vm * kk.w;
      }
    }
  }
  float* outp = vkc + (size_t)bhc * (D_*D_) + m * D_ + d0;
  #pragma unroll
  for (int j = 0; j < 16; j++) outp[j] = acc[j];
}

// ---------------- exclusive scan of VK over chunks (in place) ----------------
__global__ __launch_bounds__(256) void vk_scan_kernel(float* __restrict__ vkc){
  int idx = blockIdx.x * 256 + threadIdx.x;   // over BH*4096
  int bh = idx >> 12;
  int e  = idx & 4095;
  size_t base = ((size_t)bh * NC) * 4096 + e;
  float run = 0.f;
  for (int c = 0; c < NC; c++){
    size_t o = base + (size_t)c * 4096;
    float t = vkc[o]; vkc[o] = run; run += t;
  }
}

// ---------------- causal attention per (bh, chunk) ----------------
__global__ __launch_bounds__(256) void attn_kernel(
    const u16* __restrict__ q, const u16* __restrict__ k, const u16* __restrict__ v,
    const float* __restrict__ si, const float* __restrict__ scomp, const float* __restrict__ salloc,
    const float* __restrict__ vkc, u16* __restrict__ attnout)
{
  __shared__ __align__(16) u16 qs[128*64];    // qmod rows [l][d]
  __shared__ __align__(16) u16 ks2[128*64];   // k rows    [j][d]
  __shared__ __align__(16) u16 vts[64*128];   // (v*scomp)^T [m][j]
  __shared__ __align__(16) u16 vks[64*64];    // VKprev [m][d]
  __shared__ __align__(16) u16 ss[128*32];    // masked S strip [l][j-in-32]
  int bhc = blockIdx.x; int bh = bhc >> 5, c = bhc & 31;
  int b = bh >> 4, h = bh & 15;
  int tid = threadIdx.x, wave = tid >> 6, lane = tid & 63;
  size_t gbase = ((size_t)(b * L_ + c * CS)) * DM + h * D_;
  size_t sbase = (size_t)bh * L_ + c * CS;
  // staging
  {
    int r = tid >> 1;
    int cc = (tid & 1) * 32;
    int l = c * CS + r;
    float qscale = si[sbase + r] / (float)(l + 1);
    float vscale = scomp[sbase + r];
    #pragma unroll
    for (int j = 0; j < 4; j++){
      uint4 qu = *(const uint4*)(q + gbase + (size_t)r * DM + cc + j*8);
      uint4 kuv = *(const uint4*)(k + gbase + (size_t)r * DM + cc + j*8);
      uint4 vu = *(const uint4*)(v + gbase + (size_t)r * DM + cc + j*8);
      const u16* qp = (const u16*)&qu; const u16* vp = (const u16*)&vu;
      u16 tmp[8];
      #pragma unroll
      for (int e = 0; e < 8; e++) tmp[e] = f2bf(bf2f(qp[e]) * qscale);
      *(uint4*)&qs[r*64 + cc + j*8] = *(uint4*)tmp;
      *(uint4*)&ks2[r*64 + cc + j*8] = kuv;
      #pragma unroll
      for (int e = 0; e < 8; e++) vts[(cc + j*8 + e)*128 + r] = f2bf(bf2f(vp[e]) * vscale);
    }
    const float* vkp = vkc + (size_t)bhc * (D_*D_) + tid * 16;
    u16 tv[16];
    #pragma unroll
    for (int e = 0; e < 16; e++) tv[e] = f2bf(vkp[e]);
    *(uint4*)&vks[tid*16]   = *(uint4*)&tv[0];
    *(uint4*)&vks[tid*16+8] = *(uint4*)&tv[8];
  }
  __syncthreads();
  int t0 = wave, t1 = 7 - wave;   // balanced l-tile pair per wave
  int fr = lane & 15, kg = (lane >> 4) * 8;
  f32x4 acc[2][4];
  #pragma unroll
  for (int i=0;i<2;i++)
    #pragma unroll
    for (int j=0;j<4;j++) acc[i][j] = (f32x4){0.f,0.f,0.f,0.f};
  s16x8 aq[2][2];
  #pragma unroll
  for (int ti = 0; ti < 2; ti++){
    int t = ti ? t1 : t0;
    #pragma unroll
    for (int kk = 0; kk < 2; kk++)
      aq[ti][kk] = *(const s16x8*)&qs[(t*16 + fr)*64 + kk*32 + kg];
  }
  // inter-chunk: qmod @ VKprev^T
  #pragma unroll
  for (int mt = 0; mt < 4; mt++){
    #pragma unroll
    for (int kk = 0; kk < 2; kk++){
      s16x8 bv = *(const s16x8*)&vks[(mt*16 + fr)*64 + kk*32 + kg];
      acc[0][mt] = mfma16(aq[0][kk], bv, acc[0][mt]);
      acc[1][mt] = mfma16(aq[1][kk], bv, acc[1][mt]);
    }
  }
  // intra-chunk, 32-j strips
  for (int jt = 0; jt < 4; jt++){
    __syncthreads();
    #pragma unroll
    for (int ti = 0; ti < 2; ti++){
      int t = ti ? t1 : t0;
      #pragma unroll
      for (int u = 0; u < 2; u++){
        int jj = jt*2 + u;
        f32x4 sacc = (f32x4){0.f,0.f,0.f,0.f};
        if (jj <= t){
          #pragma unroll
          for (int kk = 0; kk < 2; kk++){
            s16x8 bkf = *(const s16x8*)&ks2[(jj*16 + fr)*64 + kk*32 + kg];
            sacc = mfma16(aq[ti][kk], bkf, sacc);
          }
        }
        int lrow = t*16 + (lane>>4)*4;
        int jcol = jj*16 + fr;
        #pragma unroll
        for (int r = 0; r < 4; r++){
          float sv = (jcol <= lrow + r) ? sacc[r] : 0.f;
          ss[(lrow + r)*32 + u*16 + fr] = f2bf(sv);
        }
      }
    }
    __syncthreads();
    #pragma unroll
    for (int ti = 0; ti < 2; ti++){
      int t = ti ? t1 : t0;
      if (jt*32 <= t*16 + 15){
        s16x8 as = *(const s16x8*)&ss[(t*16 + fr)*32 + kg];
        #pragma unroll
        for (int mt = 0; mt < 4; mt++){
          s16x8 bvv = *(const s16x8*)&vts[(mt*16 + fr)*128 + jt*32 + kg];
          acc[ti][mt] = mfma16(as, bvv, acc[ti][mt]);
        }
      }
    }
  }
  // epilogue: * sink_allocation, write bf16 [B,L,DM]
  #pragma unroll
  for (int ti = 0; ti < 2; ti++){
    int t = ti ? t1 : t0;
    int lrow = t*16 + (lane>>4)*4;
    #pragma unroll
    for (int r = 0; r < 4; r++){
      float sa = salloc[sbase + lrow + r];
      size_t orow = ((size_t)(b * L_ + c * CS + lrow + r)) * DM + h * D_;
      #pragma unroll
      for (int mt = 0; mt < 4; mt++){
        attnout[orow + mt*16 + fr] = f2bf(acc[ti][mt][r] * sa);
      }
    }
  }
}

extern "C" void kernel_launch(void* const* d_in, const int* in_sizes, int n_in,
                              void* d_out, int out_size, void* d_ws, size_t ws_size,
                              hipStream_t stream){
  (void)in_sizes; (void)n_in; (void)out_size; (void)ws_size;
  const float* x  = (const float*)d_in[0];
  const float* Wq = (const float*)d_in[1];
  const float* bq = (const float*)d_in[2];
  const float* Wk = (const float*)d_in[3];
  const float* bk = (const float*)d_in[4];
  const float* Wv = (const float*)d_in[5];
  const float* bv = (const float*)d_in[6];
  const float* Wo = (const float*)d_in[7];
  const float* bo = (const float*)d_in[8];

  char* p = (char*)d_ws;
  auto carve = [&](size_t bytes) -> void* {
    void* r = (void*)p; p += (bytes + 255) & ~(size_t)255; return r;
  };
  u16* xb  = (u16*)carve((size_t)N_*DM*2);
  u16* wqT = (u16*)carve((size_t)DM*DM*2);
  u16* wkT = (u16*)carve((size_t)DM*DM*2);
  u16* wvT = (u16*)carve((size_t)DM*DM*2);
  u16* woT = (u16*)carve((size_t)DM*DM*2);
  u16* qb  = (u16*)carve((size_t)N_*DM*2);
  u16* kb  = (u16*)carve((size_t)N_*DM*2);
  u16* vb  = (u16*)carve((size_t)N_*DM*2);
  u16* ao  = (u16*)carve((size_t)N_*DM*2);
  float* si   = (float*)carve((size_t)BH*L_*4);
  float* so   = (float*)carve((size_t)BH*L_*4);
  float* csrc = (float*)carve((size_t)BH*L_*4);
  float* sall = (float*)carve((size_t)BH*L_*4);
  float* scmp = (float*)carve((size_t)BH*L_*4);
  float* sumQ   = (float*)carve((size_t)BH*NSC*D_*4);
  float* sumK   = (float*)carve((size_t)BH*NSC*D_*4);
  float* sumQsi = (float*)carve((size_t)BH*NSC*D_*4);
  float* sumKso = (float*)carve((size_t)BH*NSC*D_*4);
  float* csSum  = (float*)carve((size_t)BH*NSC*4);
  float* csOff  = (float*)carve((size_t)BH*NSC*4);
  float* vkc    = (float*)carve((size_t)BH*NC*(size_t)(D_*D_)*4);

  // 1. conversions
  cvt_kernel<<<(N_*DM/4 + 255)/256, 256, 0, stream>>>(x, xb, N_*DM/4);
  dim3 tg(DM/64, DM/64);
  transpose_w_kernel<<<tg, 256, 0, stream>>>(Wq, wqT);
  transpose_w_kernel<<<tg, 256, 0, stream>>>(Wk, wkT);
  transpose_w_kernel<<<tg, 256, 0, stream>>>(Wv, wvT);
  transpose_w_kernel<<<tg, 256, 0, stream>>>(Wo, woT);
  // 2. projections (q,k also emit per-scan-chunk column sums)
  dim3 gg(N_/128, DM/128);
  gemm_kernel<1,0,1><<<gg, 256, 0, stream>>>(xb, wqT, bq, qb, nullptr, sumQ, N_, DM, DM);
  gemm_kernel<1,0,1><<<gg, 256, 0, stream>>>(xb, wkT, bk, kb, nullptr, sumK, N_, DM, DM);
  gemm_kernel<0,0,0><<<gg, 256, 0, stream>>>(xb, wvT, bv, vb, nullptr, nullptr, N_, DM, DM);
  // 3. normalizer pipeline
  scan2_kernel<<<BH, 64, 0, stream>>>(sumQ, sumK);
  siso_fused_kernel<<<BH*NSC, 64, 0, stream>>>(qb, kb, sumQ, sumK, si, so, sumQsi, sumKso);
  scan2_kernel<<<BH, 64, 0, stream>>>(sumQsi, sumKso);
  cons_fused_kernel<<<BH*NSC, 64, 0, stream>>>(qb, kb, si, so, sumQsi, sumKso, csrc, sall, csSum);
  cs_scan_kernel<<<BH, 64, 0, stream>>>(csSum, csOff);
  scomp_kernel<<<BH*NSC, 64, 0, stream>>>(csrc, csOff, scmp);
  // 4. causal linear attention
  vk_chunk_kernel<<<BH*NC, 256, 0, stream>>>(kb, vb, scmp, vkc);
  vk_scan_kernel<<<(BH*D_*D_)/256, 256, 0, stream>>>(vkc);
  attn_kernel<<<BH*NC, 256, 0, stream>>>(qb, kb, vb, si, scmp, sall, vkc, ao);
  // 5. output projection
  gemm_kernel<0,1,0><<<gg, 256, 0, stream>>>(ao, woT, bo, nullptr, (float*)d_out, nullptr, N_, DM, DM);
}

// Round 3
// 396.495 us; speedup vs baseline: 1.4281x; 1.1715x over previous
//
#include <hip/hip_runtime.h>
#include <stdint.h>

// Problem constants (fixed by setup_inputs)
#define B_ 4
#define L_ 4096
#define DM 1024
#define H_ 16
#define D_ 64
#define BH (B_*H_)      // 64
#define N_ (B_*L_)      // 16384
#define CS 128          // chunk size for causal attention
#define NC (L_/CS)      // 32
#define SC 64           // chunk size for normalizer scans
#define NSC (L_/SC)     // 64
#define EPSF 1e-6f

typedef unsigned short u16;
typedef unsigned int   u32;
typedef __attribute__((ext_vector_type(8))) short s16x8;
typedef __attribute__((ext_vector_type(4))) float f32x4;

__device__ __forceinline__ float bf2f(u16 u){
  union { u32 i; float f; } v; v.i = ((u32)u) << 16; return v.f;
}
__device__ __forceinline__ u16 f2bf(float f){
  union { float f; u32 i; } v; v.f = f;
  u32 i = v.i;
  return (u16)((i + 0x7fffu + ((i >> 16) & 1u)) >> 16);  // RNE
}
__device__ __forceinline__ void gload16(const void* g, void* l){
  __builtin_amdgcn_global_load_lds(
      (const __attribute__((address_space(1))) u32*)g,
      (__attribute__((address_space(3))) u32*)l, 16, 0, 0);
}
__device__ __forceinline__ f32x4 mfma16(s16x8 a, s16x8 b, f32x4 c){
  return __builtin_amdgcn_mfma_f32_16x16x32_bf16(a, b, c, 0, 0, 0);
}
__device__ __forceinline__ float sigmoidf_(float x){ return 1.0f/(1.0f+__expf(-x)); }

// ---------------- fp32 -> bf16 convert ----------------
__global__ void cvt_kernel(const float* __restrict__ in, u16* __restrict__ out, int n4){
  int i = blockIdx.x * blockDim.x + threadIdx.x;
  if (i >= n4) return;
  float4 v = ((const float4*)in)[i];
  union { u16 s[4]; uint2 u; } o;
  o.s[0]=f2bf(v.x); o.s[1]=f2bf(v.y); o.s[2]=f2bf(v.z); o.s[3]=f2bf(v.w);
  ((uint2*)out)[i] = o.u;
}

// ---------------- W [K][N] fp32 -> WT [N][K] bf16 ----------------
__global__ __launch_bounds__(256) void transpose_w_kernel(const float* __restrict__ W, u16* __restrict__ WT){
  __shared__ float t[64][65];
  int n0 = blockIdx.x * 64, k0 = blockIdx.y * 64;
  int tx = threadIdx.x & 63, ty = threadIdx.x >> 6;
  #pragma unroll
  for (int s = 0; s < 64; s += 4)
    t[ty + s][tx] = W[(size_t)(k0 + ty + s) * DM + n0 + tx];
  __syncthreads();
  #pragma unroll
  for (int s = 0; s < 64; s += 4)
    WT[(size_t)(n0 + ty + s) * DM + k0 + tx] = f2bf(t[tx][ty + s]);
}

// ---------------- 256x256 counted-vmcnt MFMA GEMM (K=1024 fixed) ----------------
// 8 waves (2M x 4N), BK=64, double-buffered swizzled LDS, prefetch distance 2 K-tiles.
// QKV=1: BT = concat [3072][1024] of WqT/WkT/WvT; sigmoid on q,k; per-scan-chunk
// column sums for q,k. QKV=0: single f32 output (Wo).
template<int QKV>
__global__ __launch_bounds__(512, 2) void gemm256_kernel(
    const u16* __restrict__ A, const u16* __restrict__ BT,
    const float* __restrict__ biasq, const float* __restrict__ biask, const float* __restrict__ biasv,
    u16* __restrict__ oq, u16* __restrict__ ok, u16* __restrict__ ov,
    float* __restrict__ outf,
    float* __restrict__ sumQ, float* __restrict__ sumK, int NBY)
{
  // LDS: A slot0 [0,32K), A slot1 [32K,64K), B slot0 [64K,96K), B slot1 [96K,128K)
  __shared__ __align__(16) u16 smem[65536];
  char* smb = (char*)smem;
  int tid = threadIdx.x;
  int wave = tid >> 6, lane = tid & 63;
  int wm = wave >> 2, wn = wave & 3;          // 2 x 4 wave grid
  // XCD-bijective block swizzle (nwg % 8 == 0 for 768 and 256)
  int nwg = gridDim.x;
  int q8 = nwg >> 3;
  int id = blockIdx.x;
  int id2 = (id & 7) * q8 + (id >> 3);
  int bx = id2 / NBY, by = id2 % NBY;
  int m0 = bx * 256, n0 = by * 256;
  // staging addresses: thread t covers row r0 = t>>3 (of 64-row pass group),
  // source chunk pre-swizzled so linear LDS dest + swizzled ds_read compose to identity
  int r0 = tid >> 3;
  int srcq = (tid & 7) ^ (r0 & 7);
  const u16* aRow = A  + (size_t)(m0 + r0) * 1024 + srcq * 8;
  const u16* bRow = BT + (size_t)(n0 + r0) * 1024 + srcq * 8;

  f32x4 acc[8][4];
  #pragma unroll
  for (int i=0;i<8;i++)
    #pragma unroll
    for (int j=0;j<4;j++) acc[i][j] = (f32x4){0.f,0.f,0.f,0.f};

  // per-lane swizzled ds_read offsets: row part fr*128, chunk = (kk*4+q) ^ (lane&7)
  int fr = lane & 15, q = lane >> 4;
  int aoff0 = fr*128 + (((q ^ (lane&3)) + 4*((lane>>2)&1)) << 4);
  int aoff1 = fr*128 + (((q ^ (lane&3)) + 4*(1 ^ ((lane>>2)&1))) << 4);

  #define STAGE(s, t) { \
    _Pragma("unroll") \
    for (int i_ = 0; i_ < 4; i_++){ \
      gload16(aRow + (size_t)(t)*64 + (size_t)i_*65536, smb + (s)*32768 + i_*8192 + tid*16); \
      gload16(bRow + (size_t)(t)*64 + (size_t)i_*65536, smb + 65536 + (s)*32768 + i_*8192 + tid*16); \
    } }

  #define COMPUTE(s) { \
    const char* Ab_ = smb + (s)*32768 + wm*16384; \
    const char* Bb_ = smb + 65536 + (s)*32768 + wn*8192; \
    _Pragma("unroll") \
    for (int kk_ = 0; kk_ < 2; kk_++){ \
      int off_ = kk_ ? aoff1 : aoff0; \
      s16x8 af_[8], bf_[4]; \
      _Pragma("unroll") \
      for (int mi_ = 0; mi_ < 8; mi_++) af_[mi_] = *(const s16x8*)(Ab_ + mi_*2048 + off_); \
      _Pragma("unroll") \
      for (int ni_ = 0; ni_ < 4; ni_++) bf_[ni_] = *(const s16x8*)(Bb_ + ni_*2048 + off_); \
      _Pragma("unroll") \
      for (int mi_ = 0; mi_ < 8; mi_++) \
        _Pragma("unroll") \
        for (int ni_ = 0; ni_ < 4; ni_++) \
          acc[mi_][ni_] = mfma16(af_[mi_], bf_[ni_], acc[mi_][ni_]); \
    } }

  // prologue: stage tiles 0,1
  STAGE(0, 0)
  STAGE(1, 1)
  // main loop over 16 K-tiles, prefetch distance 2, counted vmcnt(8)
  for (int t = 0; t < 14; t++){
    asm volatile("s_waitcnt vmcnt(8)" ::: "memory");
    __builtin_amdgcn_s_barrier();
    asm volatile("" ::: "memory");
    COMPUTE(t & 1)
    asm volatile("s_waitcnt lgkmcnt(0)" ::: "memory");
    __builtin_amdgcn_s_barrier();
    asm volatile("" ::: "memory");
    STAGE(t & 1, t + 2)
  }
  asm volatile("s_waitcnt vmcnt(8)" ::: "memory");
  __builtin_amdgcn_s_barrier();
  asm volatile("" ::: "memory");
  COMPUTE(0)
  asm volatile("s_waitcnt vmcnt(0)" ::: "memory");
  __builtin_amdgcn_s_barrier();
  asm volatile("" ::: "memory");
  COMPUTE(1)

  // epilogue
  int colblk = n0 + wn*64;                        // 64-aligned
  int which  = QKV ? (colblk >> 10) : 0;          // 0=q 1=k 2=v
  int cl0    = QKV ? (colblk & 1023) : colblk;
  const float* bias = QKV ? (which==0 ? biasq : (which==1 ? biask : biasv)) : biasq;
  u16* outp = QKV ? (which==0 ? oq : (which==1 ? ok : ov)) : (u16*)0;
  float cs0[4] = {0.f,0.f,0.f,0.f}, cs1[4] = {0.f,0.f,0.f,0.f};
  #pragma unroll
  for (int mi = 0; mi < 8; mi++){
    int row = m0 + wm*128 + mi*16 + (lane>>4)*4;
    #pragma unroll
    for (int ni = 0; ni < 4; ni++){
      int cl = cl0 + ni*16 + fr;
      float bv = bias[cl];
      #pragma unroll
      for (int r = 0; r < 4; r++){
        float val = acc[mi][ni][r] + bv;
        if (QKV){
          if (which < 2) val = sigmoidf_(val);
          outp[(size_t)(row + r) * 1024 + cl] = f2bf(val);
          if (which < 2){ if (mi < 4) cs0[ni] += val; else cs1[ni] += val; }
        } else {
          outf[(size_t)(row + r) * 1024 + cl] = val;
        }
      }
    }
  }
  if (QKV && which < 2){
    float* sums = (which==0) ? sumQ : sumK;
    int bh = (m0 >> 12) * H_ + ((colblk & 1023) >> 6);
    int sc0 = ((m0 & 4095) >> 6) + wm*2;
    #pragma unroll
    for (int h2 = 0; h2 < 2; h2++){
      #pragma unroll
      for (int ni = 0; ni < 4; ni++){
        float s = h2 ? cs1[ni] : cs0[ni];
        s += __shfl_xor(s, 16);
        s += __shfl_xor(s, 32);
        if (lane < 16) sums[((size_t)bh*NSC + sc0 + h2)*64 + ni*16 + fr] = s;
      }
    }
  }
  #undef STAGE
  #undef COMPUTE
}

// ---------------- exclusive scan over scan-chunk axis (2 arrays, in place) ----------------
__global__ __launch_bounds__(64) void scan2_kernel(float* __restrict__ A, float* __restrict__ Bv){
  int bh = blockIdx.x, d = threadIdx.x;
  float ra = 0.f, rb = 0.f;
  for (int c = 0; c < NSC; c++){
    size_t o = ((size_t)bh * NSC + c) * 64 + d;
    float ta = A[o], tb = Bv[o];
    A[o] = ra; Bv[o] = rb;
    ra += ta; rb += tb;
  }
}

// ---------------- fused sink_incoming/source_outgoing + mod chunk sums ----------------
__global__ __launch_bounds__(64) void siso_fused_kernel(
    const u16* __restrict__ q, const u16* __restrict__ k,
    const float* __restrict__ sumQx, const float* __restrict__ sumKx,
    float* __restrict__ si, float* __restrict__ so,
    float* __restrict__ sumQsi, float* __restrict__ sumKso)
{
  __shared__ float cq[64*64];
  __shared__ float ck[64*64];
  __shared__ float siv[64], sov[64];
  int bhc = blockIdx.x; int bh = bhc >> 6, sc = bhc & 63;
  int b = bh >> 4, h = bh & 15;
  int lane = threadIdx.x;
  size_t gbase = ((size_t)(b*L_ + sc*SC))*DM + h*D_;
  size_t lb = (size_t)bh*L_ + sc*SC;
  {
    float runQ = sumQx[bhc*64 + lane];
    float runK = sumKx[bhc*64 + lane];
    for (int l = 0; l < SC; l++){
      runQ += bf2f(q[gbase + (size_t)l*DM + lane]);
      runK += bf2f(k[gbase + (size_t)l*DM + lane]);
      int sw = lane ^ (l & 31);
      cq[l*64 + sw] = runQ;
      ck[l*64 + sw] = runK;
    }
  }
  __syncthreads();
  {
    int l = lane;
    const u16* qrow = q + gbase + (size_t)l*DM;
    const u16* krow = k + gbase + (size_t)l*DM;
    uint4 qr[8], kr[8];
    #pragma unroll
    for (int j=0;j<8;j++){ qr[j]=((const uint4*)qrow)[j]; kr[j]=((const uint4*)krow)[j]; }
    const u16* qp = (const u16*)qr; const u16* kp = (const u16*)kr;
    float a = 0.f, b2 = 0.f;
    #pragma unroll
    for (int d = 0; d < 64; d++){
      int sw = d ^ (l & 31);
      a  += (bf2f(qp[d])+EPSF) * (ck[l*64+sw]+EPSF);
      b2 += (bf2f(kp[d])+EPSF) * (cq[l*64+sw]+EPSF);
    }
    float n = (float)(sc*SC + l + 1);
    float vsi = n/a, vso = n/b2;
    si[lb+l] = vsi; so[lb+l] = vso;
    siv[l] = vsi;   sov[l] = vso;
  }
  __syncthreads();
  {
    float sq = 0.f, sk = 0.f;
    for (int l = 0; l < SC; l++){
      sq += bf2f(q[gbase + (size_t)l*DM + lane]) * siv[l];
      sk += bf2f(k[gbase + (size_t)l*DM + lane]) * sov[l];
    }
    sumQsi[bhc*64 + lane] = sq;
    sumKso[bhc*64 + lane] = sk;
  }
}

// ---------------- fused conserved_sink/source -> sall, csrc + exp chunk sums ----------------
__global__ __launch_bounds__(64) void cons_fused_kernel(
    const u16* __restrict__ q, const u16* __restrict__ k,
    const float* __restrict__ si, const float* __restrict__ so,
    const float* __restrict__ sumQsiX, const float* __restrict__ sumKsoX,
    float* __restrict__ csrc, float* __restrict__ sall, float* __restrict__ csSum)
{
  __shared__ float cq[64*64];
  __shared__ float ck[64*64];
  __shared__ float siv[64], sov[64];
  int bhc = blockIdx.x; int bh = bhc >> 6, sc = bhc & 63;
  int b = bh >> 4, h = bh & 15;
  int lane = threadIdx.x;
  size_t gbase = ((size_t)(b*L_ + sc*SC))*DM + h*D_;
  size_t lb = (size_t)bh*L_ + sc*SC;
  siv[lane] = si[lb + lane];
  sov[lane] = so[lb + lane];
  __syncthreads();
  {
    float runQ = sumQsiX[bhc*64 + lane];
    float runK = sumKsoX[bhc*64 + lane];
    for (int l = 0; l < SC; l++){
      runQ += bf2f(q[gbase + (size_t)l*DM + lane]) * siv[l];
      runK += bf2f(k[gbase + (size_t)l*DM + lane]) * sov[l];
      int sw = lane ^ (l & 31);
      cq[l*64 + sw] = runQ;
      ck[l*64 + sw] = runK;
    }
  }
  __syncthreads();
  {
    int l = lane;
    const u16* qrow = q + gbase + (size_t)l*DM;
    const u16* krow = k + gbase + (size_t)l*DM;
    uint4 qr[8], kr[8];
    #pragma unroll
    for (int j=0;j<8;j++){ qr[j]=((const uint4*)qrow)[j]; kr[j]=((const uint4*)krow)[j]; }
    const u16* qp = (const u16*)qr; const u16* kp = (const u16*)kr;
    float a = 0.f, b2 = 0.f;
    #pragma unroll
    for (int d = 0; d < 64; d++){
      int sw = d ^ (l & 31);
      a  += (bf2f(qp[d])+EPSF) * (ck[l*64+sw]+EPSF);
      b2 += (bf2f(kp[d])+EPSF) * (cq[l*64+sw]+EPSF);
    }
    float inv = 1.0f / (float)(sc*SC + l + 1);
    sall[lb+l] = sigmoidf_(a * inv);
    float cs = b2 * inv;
    csrc[lb+l] = cs;
    float e = __expf(cs);
    #pragma unroll
    for (int off = 32; off > 0; off >>= 1) e += __shfl_xor(e, off);
    if (lane == 0) csSum[bhc] = e;
  }
}

// ---------------- exclusive scan of exp-chunk-sums over NSC chunks ----------------
__global__ __launch_bounds__(64) void cs_scan_kernel(const float* __restrict__ csSum, float* __restrict__ csOff){
  int bh = blockIdx.x; int lane = threadIdx.x;
  float v = csSum[bh * NSC + lane];
  float run = v;
  #pragma unroll
  for (int o = 1; o < 64; o <<= 1){
    float t = __shfl_up(run, o);
    if (lane >= o) run += t;
  }
  csOff[bh * NSC + lane] = run - v;  // exclusive
}

// ---------------- source_competition ----------------
__global__ __launch_bounds__(64) void scomp_kernel(
    const float* __restrict__ csrc, const float* __restrict__ csOff,
    float* __restrict__ scomp){
  int bhc = blockIdx.x; int bh = bhc >> 6, sc = bhc & 63;
  int lane = threadIdx.x;
  size_t idx = (size_t)bh * L_ + sc * SC + lane;
  float cs = __expf(csrc[idx]);
  float run = cs;
  #pragma unroll
  for (int o = 1; o < 64; o <<= 1){
    float t = __shfl_up(run, o);
    if (lane >= o) run += t;
  }
  scomp[idx] = cs / (csOff[bh*NSC + sc] + run) * (float)(sc*SC + lane + 1);
}

// ---------------- per-chunk VK sums: VK[m][d] = sum_l v[l][m]*scomp[l]*k[l][d] ----------------
__global__ __launch_bounds__(256) void vk_chunk_kernel(
    const u16* __restrict__ k, const u16* __restrict__ v,
    const float* __restrict__ scomp, float* __restrict__ vkc){
  __shared__ float ks[32][64];
  __shared__ float vs[32][64];
  int bhc = blockIdx.x; int bh = bhc >> 5, c = bhc & 31;
  int b = bh >> 4, h = bh & 15;
  int tid = threadIdx.x;
  int m = tid >> 2, d0 = (tid & 3) * 16;
  float acc[16];
  #pragma unroll
  for (int j = 0; j < 16; j++) acc[j] = 0.f;
  size_t gbase = ((size_t)(b * L_ + c * CS)) * DM + h * D_;
  size_t sbase = (size_t)bh * L_ + c * CS;
  int r = tid >> 3, cc = (tid & 7) * 8;
  for (int s0 = 0; s0 < CS; s0 += 32){
    __syncthreads();
    float sc = scomp[sbase + s0 + r];
    uint4 ku = *(const uint4*)(k + gbase + (size_t)(s0 + r) * DM + cc);
    uint4 vu = *(const uint4*)(v + gbase + (size_t)(s0 + r) * DM + cc);
    const u16* kp = (const u16*)&ku; const u16* vp = (const u16*)&vu;
    #pragma unroll
    for (int j = 0; j < 8; j++){
      ks[r][cc + j] = bf2f(kp[j]);
      vs[r][cc + j] = bf2f(vp[j]) * sc;
    }
    __syncthreads();
    #pragma unroll
    for (int i = 0; i < 32; i++){
      float vm = vs[i][m];
      #pragma unroll
      for (int j4 = 0; j4 < 4; j4++){
        float4 kk = *(const float4*)&ks[i][d0 + j4*4];
        acc[j4*4+0] += vm * kk.x; acc[j4*4+1] += vm * kk.y;
        acc[j4*4+2] += vm * kk.z; acc[j4*4+3] += vm * kk.w;
      }
    }
  }
  float* outp = vkc + (size_t)bhc * (D_*D_) + m * D_ + d0;
  #pragma unroll
  for (int j = 0; j < 16; j++) outp[j] = acc[j];
}

// ---------------- exclusive scan of VK over chunks (in place) ----------------
__global__ __launch_bounds__(256) void vk_scan_kernel(float* __restrict__ vkc){
  int idx = blockIdx.x * 256 + threadIdx.x;   // over BH*4096
  int bh = idx >> 12;
  int e  = idx & 4095;
  size_t base = ((size_t)bh * NC) * 4096 + e;
  float run = 0.f;
  for (int c = 0; c < NC; c++){
    size_t o = base + (size_t)c * 4096;
    float t = vkc[o]; vkc[o] = run; run += t;
  }
}

// ---------------- causal attention per (bh, chunk) ----------------
__global__ __launch_bounds__(256) void attn_kernel(
    const u16* __restrict__ q, const u16* __restrict__ k, const u16* __restrict__ v,
    const float* __restrict__ si, const float* __restrict__ scomp, const float* __restrict__ salloc,
    const float* __restrict__ vkc, u16* __restrict__ attnout)
{
  __shared__ __align__(16) u16 qs[128*64];    // qmod rows [l][d]
  __shared__ __align__(16) u16 ks2[128*64];   // k rows    [j][d]
  __shared__ __align__(16) u16 vts[64*128];   // (v*scomp)^T [m][j]
  __shared__ __align__(16) u16 vks[64*64];    // VKprev [m][d]
  __shared__ __align__(16) u16 ss[128*32];    // masked S strip [l][j-in-32]
  int bhc = blockIdx.x; int bh = bhc >> 5, c = bhc & 31;
  int b = bh >> 4, h = bh & 15;
  int tid = threadIdx.x, wave = tid >> 6, lane = tid & 63;
  size_t gbase = ((size_t)(b * L_ + c * CS)) * DM + h * D_;
  size_t sbase = (size_t)bh * L_ + c * CS;
  {
    int r = tid >> 1;
    int cc = (tid & 1) * 32;
    int l = c * CS + r;
    float qscale = si[sbase + r] / (float)(l + 1);
    float vscale = scomp[sbase + r];
    #pragma unroll
    for (int j = 0; j < 4; j++){
      uint4 qu = *(const uint4*)(q + gbase + (size_t)r * DM + cc + j*8);
      uint4 kuv = *(const uint4*)(k + gbase + (size_t)r * DM + cc + j*8);
      uint4 vu = *(const uint4*)(v + gbase + (size_t)r * DM + cc + j*8);
      const u16* qp = (const u16*)&qu; const u16* vp = (const u16*)&vu;
      u16 tmp[8];
      #pragma unroll
      for (int e = 0; e < 8; e++) tmp[e] = f2bf(bf2f(qp[e]) * qscale);
      *(uint4*)&qs[r*64 + cc + j*8] = *(uint4*)tmp;
      *(uint4*)&ks2[r*64 + cc + j*8] = kuv;
      #pragma unroll
      for (int e = 0; e < 8; e++) vts[(cc + j*8 + e)*128 + r] = f2bf(bf2f(vp[e]) * vscale);
    }
    const float* vkp = vkc + (size_t)bhc * (D_*D_) + tid * 16;
    u16 tv[16];
    #pragma unroll
    for (int e = 0; e < 16; e++) tv[e] = f2bf(vkp[e]);
    *(uint4*)&vks[tid*16]   = *(uint4*)&tv[0];
    *(uint4*)&vks[tid*16+8] = *(uint4*)&tv[8];
  }
  __syncthreads();
  int t0 = wave, t1 = 7 - wave;   // balanced l-tile pair per wave
  int fr = lane & 15, kg = (lane >> 4) * 8;
  f32x4 acc[2][4];
  #pragma unroll
  for (int i=0;i<2;i++)
    #pragma unroll
    for (int j=0;j<4;j++) acc[i][j] = (f32x4){0.f,0.f,0.f,0.f};
  s16x8 aq[2][2];
  #pragma unroll
  for (int ti = 0; ti < 2; ti++){
    int t = ti ? t1 : t0;
    #pragma unroll
    for (int kk = 0; kk < 2; kk++)
      aq[ti][kk] = *(const s16x8*)&qs[(t*16 + fr)*64 + kk*32 + kg];
  }
  #pragma unroll
  for (int mt = 0; mt < 4; mt++){
    #pragma unroll
    for (int kk = 0; kk < 2; kk++){
      s16x8 bv = *(const s16x8*)&vks[(mt*16 + fr)*64 + kk*32 + kg];
      acc[0][mt] = mfma16(aq[0][kk], bv, acc[0][mt]);
      acc[1][mt] = mfma16(aq[1][kk], bv, acc[1][mt]);
    }
  }
  for (int jt = 0; jt < 4; jt++){
    __syncthreads();
    #pragma unroll
    for (int ti = 0; ti < 2; ti++){
      int t = ti ? t1 : t0;
      #pragma unroll
      for (int u = 0; u < 2; u++){
        int jj = jt*2 + u;
        f32x4 sacc = (f32x4){0.f,0.f,0.f,0.f};
        if (jj <= t){
          #pragma unroll
          for (int kk = 0; kk < 2; kk++){
            s16x8 bkf = *(const s16x8*)&ks2[(jj*16 + fr)*64 + kk*32 + kg];
            sacc = mfma16(aq[ti][kk], bkf, sacc);
          }
        }
        int lrow = t*16 + (lane>>4)*4;
        int jcol = jj*16 + fr;
        #pragma unroll
        for (int r = 0; r < 4; r++){
          float sv = (jcol <= lrow + r) ? sacc[r] : 0.f;
          ss[(lrow + r)*32 + u*16 + fr] = f2bf(sv);
        }
      }
    }
    __syncthreads();
    #pragma unroll
    for (int ti = 0; ti < 2; ti++){
      int t = ti ? t1 : t0;
      if (jt*32 <= t*16 + 15){
        s16x8 as = *(const s16x8*)&ss[(t*16 + fr)*32 + kg];
        #pragma unroll
        for (int mt = 0; mt < 4; mt++){
          s16x8 bvv = *(const s16x8*)&vts[(mt*16 + fr)*128 + jt*32 + kg];
          acc[ti][mt] = mfma16(as, bvv, acc[ti][mt]);
        }
      }
    }
  }
  #pragma unroll
  for (int ti = 0; ti < 2; ti++){
    int t = ti ? t1 : t0;
    int lrow = t*16 + (lane>>4)*4;
    #pragma unroll
    for (int r = 0; r < 4; r++){
      float sa = salloc[sbase + lrow + r];
      size_t orow = ((size_t)(b * L_ + c * CS + lrow + r)) * DM + h * D_;
      #pragma unroll
      for (int mt = 0; mt < 4; mt++){
        attnout[orow + mt*16 + fr] = f2bf(acc[ti][mt][r] * sa);
      }
    }
  }
}

extern "C" void kernel_launch(void* const* d_in, const int* in_sizes, int n_in,
                              void* d_out, int out_size, void* d_ws, size_t ws_size,
                              hipStream_t stream){
  (void)in_sizes; (void)n_in; (void)out_size; (void)ws_size;
  const float* x  = (const float*)d_in[0];
  const float* Wq = (const float*)d_in[1];
  const float* bq = (const float*)d_in[2];
  const float* Wk = (const float*)d_in[3];
  const float* bk = (const float*)d_in[4];
  const float* Wv = (const float*)d_in[5];
  const float* bv = (const float*)d_in[6];
  const float* Wo = (const float*)d_in[7];
  const float* bo = (const float*)d_in[8];

  char* p = (char*)d_ws;
  auto carve = [&](size_t bytes) -> void* {
    void* r = (void*)p; p += (bytes + 255) & ~(size_t)255; return r;
  };
  u16* xb    = (u16*)carve((size_t)N_*DM*2);
  u16* wqkvT = (u16*)carve((size_t)3*DM*DM*2);
  u16* woT   = (u16*)carve((size_t)DM*DM*2);
  u16* qb  = (u16*)carve((size_t)N_*DM*2);
  u16* kb  = (u16*)carve((size_t)N_*DM*2);
  u16* vb  = (u16*)carve((size_t)N_*DM*2);
  u16* ao  = (u16*)carve((size_t)N_*DM*2);
  float* si   = (float*)carve((size_t)BH*L_*4);
  float* so   = (float*)carve((size_t)BH*L_*4);
  float* csrc = (float*)carve((size_t)BH*L_*4);
  float* sall = (float*)carve((size_t)BH*L_*4);
  float* scmp = (float*)carve((size_t)BH*L_*4);
  float* sumQ   = (float*)carve((size_t)BH*NSC*D_*4);
  float* sumK   = (float*)carve((size_t)BH*NSC*D_*4);
  float* sumQsi = (float*)carve((size_t)BH*NSC*D_*4);
  float* sumKso = (float*)carve((size_t)BH*NSC*D_*4);
  float* csSum  = (float*)carve((size_t)BH*NSC*4);
  float* csOff  = (float*)carve((size_t)BH*NSC*4);
  float* vkc    = (float*)carve((size_t)BH*NC*(size_t)(D_*D_)*4);

  // 1. conversions
  cvt_kernel<<<(N_*DM/4 + 255)/256, 256, 0, stream>>>(x, xb, N_*DM/4);
  dim3 tg(DM/64, DM/64);
  transpose_w_kernel<<<tg, 256, 0, stream>>>(Wq, wqkvT);
  transpose_w_kernel<<<tg, 256, 0, stream>>>(Wk, wqkvT + (size_t)DM*DM);
  transpose_w_kernel<<<tg, 256, 0, stream>>>(Wv, wqkvT + (size_t)2*DM*DM);
  transpose_w_kernel<<<tg, 256, 0, stream>>>(Wo, woT);
  // 2. fused q,k,v projection (one 16384x3072x1024 GEMM) + per-scan-chunk sums
  gemm256_kernel<1><<<dim3((N_/256)*(3*DM/256)), 512, 0, stream>>>(
      xb, wqkvT, bq, bk, bv, qb, kb, vb, nullptr, sumQ, sumK, 3*DM/256);
  // 3. normalizer pipeline
  scan2_kernel<<<BH, 64, 0, stream>>>(sumQ, sumK);
  siso_fused_kernel<<<BH*NSC, 64, 0, stream>>>(qb, kb, sumQ, sumK, si, so, sumQsi, sumKso);
  scan2_kernel<<<BH, 64, 0, stream>>>(sumQsi, sumKso);
  cons_fused_kernel<<<BH*NSC, 64, 0, stream>>>(qb, kb, si, so, sumQsi, sumKso, csrc, sall, csSum);
  cs_scan_kernel<<<BH, 64, 0, stream>>>(csSum, csOff);
  scomp_kernel<<<BH*NSC, 64, 0, stream>>>(csrc, csOff, scmp);
  // 4. causal linear attention
  vk_chunk_kernel<<<BH*NC, 256, 0, stream>>>(kb, vb, scmp, vkc);
  vk_scan_kernel<<<(BH*D_*D_)/256, 256, 0, stream>>>(vkc);
  attn_kernel<<<BH*NC, 256, 0, stream>>>(qb, kb, vb, si, scmp, sall, vkc, ao);
  // 5. output projection
  gemm256_kernel<0><<<dim3((N_/256)*(DM/256)), 512, 0, stream>>>(
      ao, woT, bo, bo, bo, nullptr, nullptr, nullptr, (float*)d_out, nullptr, nullptr, DM/256);
}

// Round 4
// 395.867 us; speedup vs baseline: 1.4304x; 1.0016x over previous
//
#include <hip/hip_runtime.h>
#include <stdint.h>

// Problem constants (fixed by setup_inputs)
#define B_ 4
#define L_ 4096
#define DM 1024
#define H_ 16
#define D_ 64
#define BH (B_*H_)      // 64
#define N_ (B_*L_)      // 16384
#define CS 128          // chunk size for causal attention
#define NC (L_/CS)      // 32
#define SC 64           // chunk size for normalizer scans
#define NSC (L_/SC)     // 64
#define EPSF 1e-6f

typedef unsigned short u16;
typedef unsigned int   u32;
typedef __attribute__((ext_vector_type(8))) short s16x8;
typedef __attribute__((ext_vector_type(4))) float f32x4;

__device__ __forceinline__ float bf2f(u16 u){
  union { u32 i; float f; } v; v.i = ((u32)u) << 16; return v.f;
}
__device__ __forceinline__ u16 f2bf(float f){
  union { float f; u32 i; } v; v.f = f;
  u32 i = v.i;
  return (u16)((i + 0x7fffu + ((i >> 16) & 1u)) >> 16);  // RNE
}
__device__ __forceinline__ void gload16(const void* g, void* l){
  __builtin_amdgcn_global_load_lds(
      (const __attribute__((address_space(1))) u32*)g,
      (__attribute__((address_space(3))) u32*)l, 16, 0, 0);
}
__device__ __forceinline__ f32x4 mfma16(s16x8 a, s16x8 b, f32x4 c){
  return __builtin_amdgcn_mfma_f32_16x16x32_bf16(a, b, c, 0, 0, 0);
}
__device__ __forceinline__ float sigmoidf_(float x){ return 1.0f/(1.0f+__expf(-x)); }

// ---------------- fp32 -> bf16 convert ----------------
__global__ void cvt_kernel(const float* __restrict__ in, u16* __restrict__ out, int n4){
  int i = blockIdx.x * blockDim.x + threadIdx.x;
  if (i >= n4) return;
  float4 v = ((const float4*)in)[i];
  union { u16 s[4]; uint2 u; } o;
  o.s[0]=f2bf(v.x); o.s[1]=f2bf(v.y); o.s[2]=f2bf(v.z); o.s[3]=f2bf(v.w);
  ((uint2*)out)[i] = o.u;
}

// ---------------- 4x W [K][N] fp32 -> WT [N][K] bf16 (one launch) ----------------
__global__ __launch_bounds__(256) void transpose_w4_kernel(
    const float* __restrict__ Wq, const float* __restrict__ Wk,
    const float* __restrict__ Wv, const float* __restrict__ Wo,
    u16* __restrict__ wqkvT, u16* __restrict__ woT){
  __shared__ float t[64][65];
  int z = blockIdx.z;
  const float* W = (z==0) ? Wq : (z==1) ? Wk : (z==2) ? Wv : Wo;
  u16* WT = (z<3) ? (wqkvT + (size_t)z*DM*DM) : woT;
  int n0 = blockIdx.x * 64, k0 = blockIdx.y * 64;
  int tx = threadIdx.x & 63, ty = threadIdx.x >> 6;
  #pragma unroll
  for (int s = 0; s < 64; s += 4)
    t[ty + s][tx] = W[(size_t)(k0 + ty + s) * DM + n0 + tx];
  __syncthreads();
  #pragma unroll
  for (int s = 0; s < 64; s += 4)
    WT[(size_t)(n0 + ty + s) * DM + k0 + tx] = f2bf(t[tx][ty + s]);
}

// ---------------- 256x256 8-phase counted-vmcnt MFMA GEMM (K=1024 fixed) ----------------
// 8 waves (2M x 4N), BK=64, 16 K-tiles. A: 3 LDS buffers (prefetch distance 2),
// B: 2 buffers (distance 1). 4 phases/tile: (m-half, kk) quadrants, 16 MFMA each,
// 2 staging gloads/phase, vmcnt(4) once per tile. T2 swizzle + T5 setprio.
template<int QKV>
__global__ __launch_bounds__(512, 2) void gemm256_kernel(
    const u16* __restrict__ A, const u16* __restrict__ BT,
    const float* __restrict__ biasq, const float* __restrict__ biask, const float* __restrict__ biasv,
    u16* __restrict__ oq, u16* __restrict__ ok, u16* __restrict__ ov,
    float* __restrict__ outf,
    float* __restrict__ sumQ, float* __restrict__ sumK, int NBY)
{
  // LDS: A bufs [0,98304) = 3 x 32KB ; B bufs [98304,163840) = 2 x 32KB
  __shared__ __align__(16) u16 smem[81920];
  char* smb = (char*)smem;
  int tid = threadIdx.x;
  int wave = tid >> 6, lane = tid & 63;
  int wm = wave >> 2, wn = wave & 3;          // 2 x 4 wave grid
  // XCD-bijective block swizzle (nwg % 8 == 0 for 768 and 256)
  int nwg = gridDim.x;
  int q8 = nwg >> 3;
  int id = blockIdx.x;
  int id2 = (id & 7) * q8 + (id >> 3);
  int bx = id2 / NBY, by = id2 % NBY;
  int m0 = bx * 256, n0 = by * 256;
  // staging: thread t covers row (t>>3) of a 64-row pass group, source chunk
  // pre-swizzled so linear LDS dest + swizzled ds_read compose to identity
  int srcq = (tid & 7) ^ ((tid >> 3) & 7);
  const u16* aBase = A  + (size_t)(m0 + (tid >> 3)) * 1024 + srcq * 8;
  const u16* bBase = BT + (size_t)(n0 + (tid >> 3)) * 1024 + srcq * 8;

  f32x4 acc[8][4];
  #pragma unroll
  for (int i=0;i<8;i++)
    #pragma unroll
    for (int j=0;j<4;j++) acc[i][j] = (f32x4){0.f,0.f,0.f,0.f};

  // per-lane swizzled ds_read offsets: row fr*128, chunk = (kk*4+q) ^ (lane&7)
  int fr = lane & 15, q = lane >> 4;
  int aoff0 = fr*128 + (((q ^ (lane&3)) + 4*((lane>>2)&1)) << 4);
  int aoff1 = fr*128 + (((q ^ (lane&3)) + 4*(1 ^ ((lane>>2)&1))) << 4);

  #define STAGE_A(g, Ts, dbuf) \
    gload16(aBase + (size_t)(g)*65536 + (size_t)(Ts)*64, smb + (dbuf)*32768 + (g)*8192 + tid*16);
  #define STAGE_B(g, Ts, dbuf) \
    gload16(bBase + (size_t)(g)*65536 + (size_t)(Ts)*64, smb + 98304 + (dbuf)*32768 + (g)*8192 + tid*16);
  #define BARF() { __builtin_amdgcn_s_barrier(); asm volatile("" ::: "memory"); }
  #define PHASE_MFMA(MH) \
    __builtin_amdgcn_s_setprio(1); \
    _Pragma("unroll") \
    for (int mi=0; mi<4; mi++) \
      _Pragma("unroll") \
      for (int ni=0; ni<4; ni++) \
        acc[(MH)*4+mi][ni] = mfma16(af[mi], bfr[ni], acc[(MH)*4+mi][ni]); \
    __builtin_amdgcn_s_setprio(0);

  // prologue: A[0]->ab0, B[0]->bb0, A[1]->ab1 ; drain A[0],B[0]
  #pragma unroll
  for (int g=0; g<4; g++){ STAGE_A(g, 0, 0) }
  #pragma unroll
  for (int g=0; g<4; g++){ STAGE_B(g, 0, 0) }
  #pragma unroll
  for (int g=0; g<4; g++){ STAGE_A(g, 1, 1) }
  asm volatile("s_waitcnt vmcnt(4)" ::: "memory");
  BARF()

  int ab = 0, bb = 0;
  for (int T = 0; T < 16; T++){
    const char* Ab = smb + ab*32768 + wm*16384;
    const char* Bb = smb + 98304 + bb*32768 + wn*8192;
    int abn = ab + 2; if (abn >= 3) abn -= 3;   // (T+2)%3
    int bbn = bb ^ 1;                            // (T+1)&1
    s16x8 af[4], bfr[4];
    // P1: (mh0, kk0) — stage B[T+1] passes 0,1
    #pragma unroll
    for (int mi=0;mi<4;mi++) af[mi]  = *(const s16x8*)(Ab + mi*2048 + aoff0);
    #pragma unroll
    for (int ni=0;ni<4;ni++) bfr[ni] = *(const s16x8*)(Bb + ni*2048 + aoff0);
    if (T < 15){ STAGE_B(0, T+1, bbn) STAGE_B(1, T+1, bbn) }
    BARF()
    PHASE_MFMA(0)
    BARF()
    // P2: (mh1, kk0) — stage B[T+1] passes 2,3
    #pragma unroll
    for (int mi=0;mi<4;mi++) af[mi] = *(const s16x8*)(Ab + 8192 + mi*2048 + aoff0);
    if (T < 15){ STAGE_B(2, T+1, bbn) STAGE_B(3, T+1, bbn) }
    BARF()
    PHASE_MFMA(1)
    BARF()
    // P3: (mh0, kk1) — stage A[T+2] passes 0,1
    #pragma unroll
    for (int mi=0;mi<4;mi++) af[mi]  = *(const s16x8*)(Ab + mi*2048 + aoff1);
    #pragma unroll
    for (int ni=0;ni<4;ni++) bfr[ni] = *(const s16x8*)(Bb + ni*2048 + aoff1);
    if (T < 14){ STAGE_A(0, T+2, abn) STAGE_A(1, T+2, abn) }
    BARF()
    PHASE_MFMA(0)
    BARF()
    // P4: (mh1, kk1) — stage A[T+2] passes 2,3 ; counted vmcnt for next tile
    #pragma unroll
    for (int mi=0;mi<4;mi++) af[mi] = *(const s16x8*)(Ab + 8192 + mi*2048 + aoff1);
    if (T < 14){ STAGE_A(2, T+2, abn) STAGE_A(3, T+2, abn) }
    if (T < 14)      { asm volatile("s_waitcnt vmcnt(4)" ::: "memory"); }
    else if (T == 14){ asm volatile("s_waitcnt vmcnt(0)" ::: "memory"); }
    BARF()
    PHASE_MFMA(1)
    BARF()
    ab = (ab == 2) ? 0 : ab + 1;
    bb ^= 1;
  }

  // epilogue
  int colblk = n0 + wn*64;                        // 64-aligned
  int which  = QKV ? (colblk >> 10) : 0;          // 0=q 1=k 2=v
  int cl0    = QKV ? (colblk & 1023) : colblk;
  const float* bias = QKV ? (which==0 ? biasq : (which==1 ? biask : biasv)) : biasq;
  u16* outp = QKV ? (which==0 ? oq : (which==1 ? ok : ov)) : (u16*)0;
  float cs0[4] = {0.f,0.f,0.f,0.f}, cs1[4] = {0.f,0.f,0.f,0.f};
  #pragma unroll
  for (int mi = 0; mi < 8; mi++){
    int row = m0 + wm*128 + mi*16 + (lane>>4)*4;
    #pragma unroll
    for (int ni = 0; ni < 4; ni++){
      int cl = cl0 + ni*16 + fr;
      float bv = bias[cl];
      #pragma unroll
      for (int r = 0; r < 4; r++){
        float val = acc[mi][ni][r] + bv;
        if (QKV){
          if (which < 2) val = sigmoidf_(val);
          outp[(size_t)(row + r) * 1024 + cl] = f2bf(val);
          if (which < 2){ if (mi < 4) cs0[ni] += val; else cs1[ni] += val; }
        } else {
          outf[(size_t)(row + r) * 1024 + cl] = val;
        }
      }
    }
  }
  if (QKV && which < 2){
    float* sums = (which==0) ? sumQ : sumK;
    int bh = (m0 >> 12) * H_ + ((colblk & 1023) >> 6);
    int sc0 = ((m0 & 4095) >> 6) + wm*2;
    #pragma unroll
    for (int h2 = 0; h2 < 2; h2++){
      #pragma unroll
      for (int ni = 0; ni < 4; ni++){
        float s = h2 ? cs1[ni] : cs0[ni];
        s += __shfl_xor(s, 16);
        s += __shfl_xor(s, 32);
        if (lane < 16) sums[((size_t)bh*NSC + sc0 + h2)*64 + ni*16 + fr] = s;
      }
    }
  }
  #undef STAGE_A
  #undef STAGE_B
  #undef BARF
  #undef PHASE_MFMA
}

// ---------------- exclusive scan over scan-chunk axis (2 arrays, in place) ----------------
__global__ __launch_bounds__(64) void scan2_kernel(float* __restrict__ A, float* __restrict__ Bv){
  int bh = blockIdx.x, d = threadIdx.x;
  float ra = 0.f, rb = 0.f;
  for (int c = 0; c < NSC; c++){
    size_t o = ((size_t)bh * NSC + c) * 64 + d;
    float ta = A[o], tb = Bv[o];
    A[o] = ra; Bv[o] = rb;
    ra += ta; rb += tb;
  }
}

// ---------------- fused sink_incoming/source_outgoing + mod chunk sums ----------------
__global__ __launch_bounds__(64) void siso_fused_kernel(
    const u16* __restrict__ q, const u16* __restrict__ k,
    const float* __restrict__ sumQx, const float* __restrict__ sumKx,
    float* __restrict__ si, float* __restrict__ so,
    float* __restrict__ sumQsi, float* __restrict__ sumKso)
{
  __shared__ float cq[64*64];
  __shared__ float ck[64*64];
  __shared__ float siv[64], sov[64];
  int bhc = blockIdx.x; int bh = bhc >> 6, sc = bhc & 63;
  int b = bh >> 4, h = bh & 15;
  int lane = threadIdx.x;
  size_t gbase = ((size_t)(b*L_ + sc*SC))*DM + h*D_;
  size_t lb = (size_t)bh*L_ + sc*SC;
  {
    float runQ = sumQx[bhc*64 + lane];
    float runK = sumKx[bhc*64 + lane];
    for (int l = 0; l < SC; l++){
      runQ += bf2f(q[gbase + (size_t)l*DM + lane]);
      runK += bf2f(k[gbase + (size_t)l*DM + lane]);
      int sw = lane ^ (l & 31);
      cq[l*64 + sw] = runQ;
      ck[l*64 + sw] = runK;
    }
  }
  __syncthreads();
  {
    int l = lane;
    const u16* qrow = q + gbase + (size_t)l*DM;
    const u16* krow = k + gbase + (size_t)l*DM;
    uint4 qr[8], kr[8];
    #pragma unroll
    for (int j=0;j<8;j++){ qr[j]=((const uint4*)qrow)[j]; kr[j]=((const uint4*)krow)[j]; }
    const u16* qp = (const u16*)qr; const u16* kp = (const u16*)kr;
    float a = 0.f, b2 = 0.f;
    #pragma unroll
    for (int d = 0; d < 64; d++){
      int sw = d ^ (l & 31);
      a  += (bf2f(qp[d])+EPSF) * (ck[l*64+sw]+EPSF);
      b2 += (bf2f(kp[d])+EPSF) * (cq[l*64+sw]+EPSF);
    }
    float n = (float)(sc*SC + l + 1);
    float vsi = n/a, vso = n/b2;
    si[lb+l] = vsi; so[lb+l] = vso;
    siv[l] = vsi;   sov[l] = vso;
  }
  __syncthreads();
  {
    float sq = 0.f, sk = 0.f;
    for (int l = 0; l < SC; l++){
      sq += bf2f(q[gbase + (size_t)l*DM + lane]) * siv[l];
      sk += bf2f(k[gbase + (size_t)l*DM + lane]) * sov[l];
    }
    sumQsi[bhc*64 + lane] = sq;
    sumKso[bhc*64 + lane] = sk;
  }
}

// ---------------- fused conserved_sink/source -> sall, csrc + exp chunk sums ----------------
__global__ __launch_bounds__(64) void cons_fused_kernel(
    const u16* __restrict__ q, const u16* __restrict__ k,
    const float* __restrict__ si, const float* __restrict__ so,
    const float* __restrict__ sumQsiX, const float* __restrict__ sumKsoX,
    float* __restrict__ csrc, float* __restrict__ sall, float* __restrict__ csSum)
{
  __shared__ float cq[64*64];
  __shared__ float ck[64*64];
  __shared__ float siv[64], sov[64];
  int bhc = blockIdx.x; int bh = bhc >> 6, sc = bhc & 63;
  int b = bh >> 4, h = bh & 15;
  int lane = threadIdx.x;
  size_t gbase = ((size_t)(b*L_ + sc*SC))*DM + h*D_;
  size_t lb = (size_t)bh*L_ + sc*SC;
  siv[lane] = si[lb + lane];
  sov[lane] = so[lb + lane];
  __syncthreads();
  {
    float runQ = sumQsiX[bhc*64 + lane];
    float runK = sumKsoX[bhc*64 + lane];
    for (int l = 0; l < SC; l++){
      runQ += bf2f(q[gbase + (size_t)l*DM + lane]) * siv[l];
      runK += bf2f(k[gbase + (size_t)l*DM + lane]) * sov[l];
      int sw = lane ^ (l & 31);
      cq[l*64 + sw] = runQ;
      ck[l*64 + sw] = runK;
    }
  }
  __syncthreads();
  {
    int l = lane;
    const u16* qrow = q + gbase + (size_t)l*DM;
    const u16* krow = k + gbase + (size_t)l*DM;
    uint4 qr[8], kr[8];
    #pragma unroll
    for (int j=0;j<8;j++){ qr[j]=((const uint4*)qrow)[j]; kr[j]=((const uint4*)krow)[j]; }
    const u16* qp = (const u16*)qr; const u16* kp = (const u16*)kr;
    float a = 0.f, b2 = 0.f;
    #pragma unroll
    for (int d = 0; d < 64; d++){
      int sw = d ^ (l & 31);
      a  += (bf2f(qp[d])+EPSF) * (ck[l*64+sw]+EPSF);
      b2 += (bf2f(kp[d])+EPSF) * (cq[l*64+sw]+EPSF);
    }
    float inv = 1.0f / (float)(sc*SC + l + 1);
    sall[lb+l] = sigmoidf_(a * inv);
    float cs = b2 * inv;
    csrc[lb+l] = cs;
    float e = __expf(cs);
    #pragma unroll
    for (int off = 32; off > 0; off >>= 1) e += __shfl_xor(e, off);
    if (lane == 0) csSum[bhc] = e;
  }
}

// ---------------- exclusive scan of exp-chunk-sums over NSC chunks ----------------
__global__ __launch_bounds__(64) void cs_scan_kernel(const float* __restrict__ csSum, float* __restrict__ csOff){
  int bh = blockIdx.x; int lane = threadIdx.x;
  float v = csSum[bh * NSC + lane];
  float run = v;
  #pragma unroll
  for (int o = 1; o < 64; o <<= 1){
    float t = __shfl_up(run, o);
    if (lane >= o) run += t;
  }
  csOff[bh * NSC + lane] = run - v;  // exclusive
}

// ---------------- source_competition ----------------
__global__ __launch_bounds__(64) void scomp_kernel(
    const float* __restrict__ csrc, const float* __restrict__ csOff,
    float* __restrict__ scomp){
  int bhc = blockIdx.x; int bh = bhc >> 6, sc = bhc & 63;
  int lane = threadIdx.x;
  size_t idx = (size_t)bh * L_ + sc * SC + lane;
  float cs = __expf(csrc[idx]);
  float run = cs;
  #pragma unroll
  for (int o = 1; o < 64; o <<= 1){
    float t = __shfl_up(run, o);
    if (lane >= o) run += t;
  }
  scomp[idx] = cs / (csOff[bh*NSC + sc] + run) * (float)(sc*SC + lane + 1);
}

// ---------------- per-chunk VK sums: VK[m][d] = sum_l v[l][m]*scomp[l]*k[l][d] ----------------
__global__ __launch_bounds__(256) void vk_chunk_kernel(
    const u16* __restrict__ k, const u16* __restrict__ v,
    const float* __restrict__ scomp, float* __restrict__ vkc){
  __shared__ float ks[32][64];
  __shared__ float vs[32][64];
  int bhc = blockIdx.x; int bh = bhc >> 5, c = bhc & 31;
  int b = bh >> 4, h = bh & 15;
  int tid = threadIdx.x;
  int m = tid >> 2, d0 = (tid & 3) * 16;
  float acc[16];
  #pragma unroll
  for (int j = 0; j < 16; j++) acc[j] = 0.f;
  size_t gbase = ((size_t)(b * L_ + c * CS)) * DM + h * D_;
  size_t sbase = (size_t)bh * L_ + c * CS;
  int r = tid >> 3, cc = (tid & 7) * 8;
  for (int s0 = 0; s0 < CS; s0 += 32){
    __syncthreads();
    float sc = scomp[sbase + s0 + r];
    uint4 ku = *(const uint4*)(k + gbase + (size_t)(s0 + r) * DM + cc);
    uint4 vu = *(const uint4*)(v + gbase + (size_t)(s0 + r) * DM + cc);
    const u16* kp = (const u16*)&ku; const u16* vp = (const u16*)&vu;
    #pragma unroll
    for (int j = 0; j < 8; j++){
      ks[r][cc + j] = bf2f(kp[j]);
      vs[r][cc + j] = bf2f(vp[j]) * sc;
    }
    __syncthreads();
    #pragma unroll
    for (int i = 0; i < 32; i++){
      float vm = vs[i][m];
      #pragma unroll
      for (int j4 = 0; j4 < 4; j4++){
        float4 kk = *(const float4*)&ks[i][d0 + j4*4];
        acc[j4*4+0] += vm * kk.x; acc[j4*4+1] += vm * kk.y;
        acc[j4*4+2] += vm * kk.z; acc[j4*4+3] += vm * kk.w;
      }
    }
  }
  float* outp = vkc + (size_t)bhc * (D_*D_) + m * D_ + d0;
  #pragma unroll
  for (int j = 0; j < 16; j++) outp[j] = acc[j];
}

// ---------------- exclusive scan of VK over chunks (in place) ----------------
__global__ __launch_bounds__(256) void vk_scan_kernel(float* __restrict__ vkc){
  int idx = blockIdx.x * 256 + threadIdx.x;   // over BH*4096
  int bh = idx >> 12;
  int e  = idx & 4095;
  size_t base = ((size_t)bh * NC) * 4096 + e;
  float run = 0.f;
  for (int c = 0; c < NC; c++){
    size_t o = base + (size_t)c * 4096;
    float t = vkc[o]; vkc[o] = run; run += t;
  }
}

// ---------------- causal attention per (bh, chunk) ----------------
__global__ __launch_bounds__(256) void attn_kernel(
    const u16* __restrict__ q, const u16* __restrict__ k, const u16* __restrict__ v,
    const float* __restrict__ si, const float* __restrict__ scomp, const float* __restrict__ salloc,
    const float* __restrict__ vkc, u16* __restrict__ attnout)
{
  __shared__ __align__(16) u16 qs[128*64];    // qmod rows [l][d]
  __shared__ __align__(16) u16 ks2[128*64];   // k rows    [j][d]
  __shared__ __align__(16) u16 vts[64*128];   // (v*scomp)^T [m][j]
  __shared__ __align__(16) u16 vks[64*64];    // VKprev [m][d]
  __shared__ __align__(16) u16 ss[128*32];    // masked S strip [l][j-in-32]
  int bhc = blockIdx.x; int bh = bhc >> 5, c = bhc & 31;
  int b = bh >> 4, h = bh & 15;
  int tid = threadIdx.x, wave = tid >> 6, lane = tid & 63;
  size_t gbase = ((size_t)(b * L_ + c * CS)) * DM + h * D_;
  size_t sbase = (size_t)bh * L_ + c * CS;
  {
    int r = tid >> 1;
    int cc = (tid & 1) * 32;
    int l = c * CS + r;
    float qscale = si[sbase + r] / (float)(l + 1);
    float vscale = scomp[sbase + r];
    #pragma unroll
    for (int j = 0; j < 4; j++){
      uint4 qu = *(const uint4*)(q + gbase + (size_t)r * DM + cc + j*8);
      uint4 kuv = *(const uint4*)(k + gbase + (size_t)r * DM + cc + j*8);
      uint4 vu = *(const uint4*)(v + gbase + (size_t)r * DM + cc + j*8);
      const u16* qp = (const u16*)&qu; const u16* vp = (const u16*)&vu;
      u16 tmp[8];
      #pragma unroll
      for (int e = 0; e < 8; e++) tmp[e] = f2bf(bf2f(qp[e]) * qscale);
      *(uint4*)&qs[r*64 + cc + j*8] = *(uint4*)tmp;
      *(uint4*)&ks2[r*64 + cc + j*8] = kuv;
      #pragma unroll
      for (int e = 0; e < 8; e++) vts[(cc + j*8 + e)*128 + r] = f2bf(bf2f(vp[e]) * vscale);
    }
    const float* vkp = vkc + (size_t)bhc * (D_*D_) + tid * 16;
    u16 tv[16];
    #pragma unroll
    for (int e = 0; e < 16; e++) tv[e] = f2bf(vkp[e]);
    *(uint4*)&vks[tid*16]   = *(uint4*)&tv[0];
    *(uint4*)&vks[tid*16+8] = *(uint4*)&tv[8];
  }
  __syncthreads();
  int t0 = wave, t1 = 7 - wave;   // balanced l-tile pair per wave
  int fr = lane & 15, kg = (lane >> 4) * 8;
  f32x4 acc[2][4];
  #pragma unroll
  for (int i=0;i<2;i++)
    #pragma unroll
    for (int j=0;j<4;j++) acc[i][j] = (f32x4){0.f,0.f,0.f,0.f};
  s16x8 aq[2][2];
  #pragma unroll
  for (int ti = 0; ti < 2; ti++){
    int t = ti ? t1 : t0;
    #pragma unroll
    for (int kk = 0; kk < 2; kk++)
      aq[ti][kk] = *(const s16x8*)&qs[(t*16 + fr)*64 + kk*32 + kg];
  }
  #pragma unroll
  for (int mt = 0; mt < 4; mt++){
    #pragma unroll
    for (int kk = 0; kk < 2; kk++){
      s16x8 bv = *(const s16x8*)&vks[(mt*16 + fr)*64 + kk*32 + kg];
      acc[0][mt] = mfma16(aq[0][kk], bv, acc[0][mt]);
      acc[1][mt] = mfma16(aq[1][kk], bv, acc[1][mt]);
    }
  }
  for (int jt = 0; jt < 4; jt++){
    __syncthreads();
    #pragma unroll
    for (int ti = 0; ti < 2; ti++){
      int t = ti ? t1 : t0;
      #pragma unroll
      for (int u = 0; u < 2; u++){
        int jj = jt*2 + u;
        f32x4 sacc = (f32x4){0.f,0.f,0.f,0.f};
        if (jj <= t){
          #pragma unroll
          for (int kk = 0; kk < 2; kk++){
            s16x8 bkf = *(const s16x8*)&ks2[(jj*16 + fr)*64 + kk*32 + kg];
            sacc = mfma16(aq[ti][kk], bkf, sacc);
          }
        }
        int lrow = t*16 + (lane>>4)*4;
        int jcol = jj*16 + fr;
        #pragma unroll
        for (int r = 0; r < 4; r++){
          float sv = (jcol <= lrow + r) ? sacc[r] : 0.f;
          ss[(lrow + r)*32 + u*16 + fr] = f2bf(sv);
        }
      }
    }
    __syncthreads();
    #pragma unroll
    for (int ti = 0; ti < 2; ti++){
      int t = ti ? t1 : t0;
      if (jt*32 <= t*16 + 15){
        s16x8 as = *(const s16x8*)&ss[(t*16 + fr)*32 + kg];
        #pragma unroll
        for (int mt = 0; mt < 4; mt++){
          s16x8 bvv = *(const s16x8*)&vts[(mt*16 + fr)*128 + jt*32 + kg];
          acc[ti][mt] = mfma16(as, bvv, acc[ti][mt]);
        }
      }
    }
  }
  #pragma unroll
  for (int ti = 0; ti < 2; ti++){
    int t = ti ? t1 : t0;
    int lrow = t*16 + (lane>>4)*4;
    #pragma unroll
    for (int r = 0; r < 4; r++){
      float sa = salloc[sbase + lrow + r];
      size_t orow = ((size_t)(b * L_ + c * CS + lrow + r)) * DM + h * D_;
      #pragma unroll
      for (int mt = 0; mt < 4; mt++){
        attnout[orow + mt*16 + fr] = f2bf(acc[ti][mt][r] * sa);
      }
    }
  }
}

extern "C" void kernel_launch(void* const* d_in, const int* in_sizes, int n_in,
                              void* d_out, int out_size, void* d_ws, size_t ws_size,
                              hipStream_t stream){
  (void)in_sizes; (void)n_in; (void)out_size; (void)ws_size;
  const float* x  = (const float*)d_in[0];
  const float* Wq = (const float*)d_in[1];
  const float* bq = (const float*)d_in[2];
  const float* Wk = (const float*)d_in[3];
  const float* bk = (const float*)d_in[4];
  const float* Wv = (const float*)d_in[5];
  const float* bv = (const float*)d_in[6];
  const float* Wo = (const float*)d_in[7];
  const float* bo = (const float*)d_in[8];

  char* p = (char*)d_ws;
  auto carve = [&](size_t bytes) -> void* {
    void* r = (void*)p; p += (bytes + 255) & ~(size_t)255; return r;
  };
  u16* xb    = (u16*)carve((size_t)N_*DM*2);
  u16* wqkvT = (u16*)carve((size_t)3*DM*DM*2);
  u16* woT   = (u16*)carve((size_t)DM*DM*2);
  u16* qb  = (u16*)carve((size_t)N_*DM*2);
  u16* kb  = (u16*)carve((size_t)N_*DM*2);
  u16* vb  = (u16*)carve((size_t)N_*DM*2);
  u16* ao  = (u16*)carve((size_t)N_*DM*2);
  float* si   = (float*)carve((size_t)BH*L_*4);
  float* so   = (float*)carve((size_t)BH*L_*4);
  float* csrc = (float*)carve((size_t)BH*L_*4);
  float* sall = (float*)carve((size_t)BH*L_*4);
  float* scmp = (float*)carve((size_t)BH*L_*4);
  float* sumQ   = (float*)carve((size_t)BH*NSC*D_*4);
  float* sumK   = (float*)carve((size_t)BH*NSC*D_*4);
  float* sumQsi = (float*)carve((size_t)BH*NSC*D_*4);
  float* sumKso = (float*)carve((size_t)BH*NSC*D_*4);
  float* csSum  = (float*)carve((size_t)BH*NSC*4);
  float* csOff  = (float*)carve((size_t)BH*NSC*4);
  float* vkc    = (float*)carve((size_t)BH*NC*(size_t)(D_*D_)*4);

  // 1. conversions
  cvt_kernel<<<(N_*DM/4 + 255)/256, 256, 0, stream>>>(x, xb, N_*DM/4);
  transpose_w4_kernel<<<dim3(DM/64, DM/64, 4), 256, 0, stream>>>(Wq, Wk, Wv, Wo, wqkvT, woT);
  // 2. fused q,k,v projection (one 16384x3072x1024 GEMM) + per-scan-chunk sums
  gemm256_kernel<1><<<dim3((N_/256)*(3*DM/256)), 512, 0, stream>>>(
      xb, wqkvT, bq, bk, bv, qb, kb, vb, nullptr, sumQ, sumK, 3*DM/256);
  // 3. normalizer pipeline
  scan2_kernel<<<BH, 64, 0, stream>>>(sumQ, sumK);
  siso_fused_kernel<<<BH*NSC, 64, 0, stream>>>(qb, kb, sumQ, sumK, si, so, sumQsi, sumKso);
  scan2_kernel<<<BH, 64, 0, stream>>>(sumQsi, sumKso);
  cons_fused_kernel<<<BH*NSC, 64, 0, stream>>>(qb, kb, si, so, sumQsi, sumKso, csrc, sall, csSum);
  cs_scan_kernel<<<BH, 64, 0, stream>>>(csSum, csOff);
  scomp_kernel<<<BH*NSC, 64, 0, stream>>>(csrc, csOff, scmp);
  // 4. causal linear attention
  vk_chunk_kernel<<<BH*NC, 256, 0, stream>>>(kb, vb, scmp, vkc);
  vk_scan_kernel<<<(BH*D_*D_)/256, 256, 0, stream>>>(vkc);
  attn_kernel<<<BH*NC, 256, 0, stream>>>(qb, kb, vb, si, scmp, sall, vkc, ao);
  // 5. output projection
  gemm256_kernel<0><<<dim3((N_/256)*(DM/256)), 512, 0, stream>>>(
      ao, woT, bo, bo, bo, nullptr, nullptr, nullptr, (float*)d_out, nullptr, nullptr, DM/256);
}

// Round 5
// 392.515 us; speedup vs baseline: 1.4426x; 1.0085x over previous
//
#include <hip/hip_runtime.h>
#include <stdint.h>

// Problem constants (fixed by setup_inputs)
#define B_ 4
#define L_ 4096
#define DM 1024
#define H_ 16
#define D_ 64
#define BH (B_*H_)      // 64
#define N_ (B_*L_)      // 16384
#define CS 128          // chunk size for causal attention
#define NC (L_/CS)      // 32
#define SC 64           // chunk size for normalizer scans
#define NSC (L_/SC)     // 64
#define EPSF 1e-6f

typedef unsigned short u16;
typedef unsigned int   u32;
typedef __attribute__((ext_vector_type(8))) short s16x8;
typedef __attribute__((ext_vector_type(4))) float f32x4;

__device__ __forceinline__ float bf2f(u16 u){
  union { u32 i; float f; } v; v.i = ((u32)u) << 16; return v.f;
}
__device__ __forceinline__ u16 f2bf(float f){
  union { float f; u32 i; } v; v.f = f;
  u32 i = v.i;
  return (u16)((i + 0x7fffu + ((i >> 16) & 1u)) >> 16);  // RNE
}
__device__ __forceinline__ void gload16(const void* g, void* l){
  __builtin_amdgcn_global_load_lds(
      (const __attribute__((address_space(1))) u32*)g,
      (__attribute__((address_space(3))) u32*)l, 16, 0, 0);
}
__device__ __forceinline__ f32x4 mfma16(s16x8 a, s16x8 b, f32x4 c){
  return __builtin_amdgcn_mfma_f32_16x16x32_bf16(a, b, c, 0, 0, 0);
}
__device__ __forceinline__ float sigmoidf_(float x){ return 1.0f/(1.0f+__expf(-x)); }

// ---------------- fp32 -> bf16 convert ----------------
__global__ void cvt_kernel(const float* __restrict__ in, u16* __restrict__ out, int n4){
  int i = blockIdx.x * blockDim.x + threadIdx.x;
  if (i >= n4) return;
  float4 v = ((const float4*)in)[i];
  union { u16 s[4]; uint2 u; } o;
  o.s[0]=f2bf(v.x); o.s[1]=f2bf(v.y); o.s[2]=f2bf(v.z); o.s[3]=f2bf(v.w);
  ((uint2*)out)[i] = o.u;
}

// ---------------- 4x W [K][N] fp32 -> WT [N][K] bf16 (one launch) ----------------
__global__ __launch_bounds__(256) void transpose_w4_kernel(
    const float* __restrict__ Wq, const float* __restrict__ Wk,
    const float* __restrict__ Wv, const float* __restrict__ Wo,
    u16* __restrict__ wqkvT, u16* __restrict__ woT){
  __shared__ float t[64][65];
  int z = blockIdx.z;
  const float* W = (z==0) ? Wq : (z==1) ? Wk : (z==2) ? Wv : Wo;
  u16* WT = (z<3) ? (wqkvT + (size_t)z*DM*DM) : woT;
  int n0 = blockIdx.x * 64, k0 = blockIdx.y * 64;
  int tx = threadIdx.x & 63, ty = threadIdx.x >> 6;
  #pragma unroll
  for (int s = 0; s < 64; s += 4)
    t[ty + s][tx] = W[(size_t)(k0 + ty + s) * DM + n0 + tx];
  __syncthreads();
  #pragma unroll
  for (int s = 0; s < 64; s += 4)
    WT[(size_t)(n0 + ty + s) * DM + k0 + tx] = f2bf(t[tx][ty + s]);
}

// ---------------- 256x256 8-phase counted-vmcnt MFMA GEMM (K=1024 fixed) ----------------
// 8 waves (2M x 4N), BK=64, 16 K-tiles. A: 3 LDS buffers (prefetch distance 2),
// B: 2 buffers (distance 1). 4 phases/tile, 16 MFMA each, 2 staging gloads/phase,
// vmcnt(4) once per tile. T2 swizzle + T5 setprio + sched_barrier(0) MFMA pinning
// (rule #18: "memory" clobbers do NOT order register-only MFMA; without the
// sched_barrier fence the compiler hoists MFMA above s_barrier and the phase
// structure collapses back to 2-phase — observed R3==R4 counters).
template<int QKV>
__global__ __launch_bounds__(512, 2) void gemm256_kernel(
    const u16* __restrict__ A, const u16* __restrict__ BT,
    const float* __restrict__ biasq, const float* __restrict__ biask, const float* __restrict__ biasv,
    u16* __restrict__ oq, u16* __restrict__ ok, u16* __restrict__ ov,
    float* __restrict__ outf,
    float* __restrict__ sumQ, float* __restrict__ sumK, int NBY)
{
  // LDS: A bufs [0,98304) = 3 x 32KB ; B bufs [98304,163840) = 2 x 32KB
  __shared__ __align__(16) u16 smem[81920];
  char* smb = (char*)smem;
  int tid = threadIdx.x;
  int wave = tid >> 6, lane = tid & 63;
  int wm = wave >> 2, wn = wave & 3;          // 2 x 4 wave grid
  // XCD-bijective block swizzle (nwg % 8 == 0 for 768 and 256)
  int nwg = gridDim.x;
  int q8 = nwg >> 3;
  int id = blockIdx.x;
  int id2 = (id & 7) * q8 + (id >> 3);
  int bx = id2 / NBY, by = id2 % NBY;
  int m0 = bx * 256, n0 = by * 256;
  // staging: thread t covers row (t>>3) of a 64-row pass group, source chunk
  // pre-swizzled so linear LDS dest + swizzled ds_read compose to identity
  int srcq = (tid & 7) ^ ((tid >> 3) & 7);
  const u16* aBase = A  + (size_t)(m0 + (tid >> 3)) * 1024 + srcq * 8;
  const u16* bBase = BT + (size_t)(n0 + (tid >> 3)) * 1024 + srcq * 8;

  f32x4 acc[8][4];
  #pragma unroll
  for (int i=0;i<8;i++)
    #pragma unroll
    for (int j=0;j<4;j++) acc[i][j] = (f32x4){0.f,0.f,0.f,0.f};

  // per-lane swizzled ds_read offsets: row fr*128, chunk = (kk*4+q) ^ (lane&7)
  int fr = lane & 15, q = lane >> 4;
  int aoff0 = fr*128 + (((q ^ (lane&3)) + 4*((lane>>2)&1)) << 4);
  int aoff1 = fr*128 + (((q ^ (lane&3)) + 4*(1 ^ ((lane>>2)&1))) << 4);

  #define STAGE_A(g, Ts, dbuf) \
    gload16(aBase + (size_t)(g)*65536 + (size_t)(Ts)*64, smb + (dbuf)*32768 + (g)*8192 + tid*16);
  #define STAGE_B(g, Ts, dbuf) \
    gload16(bBase + (size_t)(g)*65536 + (size_t)(Ts)*64, smb + 98304 + (dbuf)*32768 + (g)*8192 + tid*16);
  // barrier -> lgkm drain -> hard scheduling fence (pins MFMA cluster below)
  #define BAR_IN() { \
    __builtin_amdgcn_s_barrier(); \
    asm volatile("s_waitcnt lgkmcnt(0)" ::: "memory"); \
    __builtin_amdgcn_sched_barrier(0); }
  // hard fence -> barrier (pins MFMA cluster above)
  #define BAR_OUT() { \
    __builtin_amdgcn_sched_barrier(0); \
    __builtin_amdgcn_s_barrier(); }
  #define PHASE_MFMA(MH) \
    __builtin_amdgcn_s_setprio(1); \
    _Pragma("unroll") \
    for (int mi=0; mi<4; mi++) \
      _Pragma("unroll") \
      for (int ni=0; ni<4; ni++) \
        acc[(MH)*4+mi][ni] = mfma16(af[mi], bfr[ni], acc[(MH)*4+mi][ni]); \
    __builtin_amdgcn_s_setprio(0);

  // prologue: A[0]->ab0, B[0]->bb0, A[1]->ab1 ; drain A[0],B[0]
  #pragma unroll
  for (int g=0; g<4; g++){ STAGE_A(g, 0, 0) }
  #pragma unroll
  for (int g=0; g<4; g++){ STAGE_B(g, 0, 0) }
  #pragma unroll
  for (int g=0; g<4; g++){ STAGE_A(g, 1, 1) }
  asm volatile("s_waitcnt vmcnt(4)" ::: "memory");
  __builtin_amdgcn_s_barrier();

  int ab = 0, bb = 0;
  for (int T = 0; T < 16; T++){
    const char* Ab = smb + ab*32768 + wm*16384;
    const char* Bb = smb + 98304 + bb*32768 + wn*8192;
    int abn = ab + 2; if (abn >= 3) abn -= 3;   // (T+2)%3
    int bbn = bb ^ 1;                            // (T+1)&1
    s16x8 af[4], bfr[4];
    // P1: (mh0, kk0) — stage B[T+1] passes 0,1
    #pragma unroll
    for (int mi=0;mi<4;mi++) af[mi]  = *(const s16x8*)(Ab + mi*2048 + aoff0);
    #pragma unroll
    for (int ni=0;ni<4;ni++) bfr[ni] = *(const s16x8*)(Bb + ni*2048 + aoff0);
    if (T < 15){ STAGE_B(0, T+1, bbn) STAGE_B(1, T+1, bbn) }
    BAR_IN()
    PHASE_MFMA(0)
    BAR_OUT()
    // P2: (mh1, kk0) — stage B[T+1] passes 2,3
    #pragma unroll
    for (int mi=0;mi<4;mi++) af[mi] = *(const s16x8*)(Ab + 8192 + mi*2048 + aoff0);
    if (T < 15){ STAGE_B(2, T+1, bbn) STAGE_B(3, T+1, bbn) }
    BAR_IN()
    PHASE_MFMA(1)
    BAR_OUT()
    // P3: (mh0, kk1) — stage A[T+2] passes 0,1
    #pragma unroll
    for (int mi=0;mi<4;mi++) af[mi]  = *(const s16x8*)(Ab + mi*2048 + aoff1);
    #pragma unroll
    for (int ni=0;ni<4;ni++) bfr[ni] = *(const s16x8*)(Bb + ni*2048 + aoff1);
    if (T < 14){ STAGE_A(0, T+2, abn) STAGE_A(1, T+2, abn) }
    BAR_IN()
    PHASE_MFMA(0)
    BAR_OUT()
    // P4: (mh1, kk1) — stage A[T+2] passes 2,3 ; counted vmcnt for next tile
    #pragma unroll
    for (int mi=0;mi<4;mi++) af[mi] = *(const s16x8*)(Ab + 8192 + mi*2048 + aoff1);
    if (T < 14){ STAGE_A(2, T+2, abn) STAGE_A(3, T+2, abn) }
    if (T < 14)      { asm volatile("s_waitcnt vmcnt(4)" ::: "memory"); }
    else if (T == 14){ asm volatile("s_waitcnt vmcnt(0)" ::: "memory"); }
    BAR_IN()
    PHASE_MFMA(1)
    BAR_OUT()
    ab = (ab == 2) ? 0 : ab + 1;
    bb ^= 1;
  }

  // epilogue
  int colblk = n0 + wn*64;                        // 64-aligned
  int which  = QKV ? (colblk >> 10) : 0;          // 0=q 1=k 2=v
  int cl0    = QKV ? (colblk & 1023) : colblk;
  const float* bias = QKV ? (which==0 ? biasq : (which==1 ? biask : biasv)) : biasq;
  u16* outp = QKV ? (which==0 ? oq : (which==1 ? ok : ov)) : (u16*)0;
  float cs0[4] = {0.f,0.f,0.f,0.f}, cs1[4] = {0.f,0.f,0.f,0.f};
  #pragma unroll
  for (int mi = 0; mi < 8; mi++){
    int row = m0 + wm*128 + mi*16 + (lane>>4)*4;
    #pragma unroll
    for (int ni = 0; ni < 4; ni++){
      int cl = cl0 + ni*16 + fr;
      float bv = bias[cl];
      #pragma unroll
      for (int r = 0; r < 4; r++){
        float val = acc[mi][ni][r] + bv;
        if (QKV){
          if (which < 2) val = sigmoidf_(val);
          outp[(size_t)(row + r) * 1024 + cl] = f2bf(val);
          if (which < 2){ if (mi < 4) cs0[ni] += val; else cs1[ni] += val; }
        } else {
          outf[(size_t)(row + r) * 1024 + cl] = val;
        }
      }
    }
  }
  if (QKV && which < 2){
    float* sums = (which==0) ? sumQ : sumK;
    int bh = (m0 >> 12) * H_ + ((colblk & 1023) >> 6);
    int sc0 = ((m0 & 4095) >> 6) + wm*2;
    #pragma unroll
    for (int h2 = 0; h2 < 2; h2++){
      #pragma unroll
      for (int ni = 0; ni < 4; ni++){
        float s = h2 ? cs1[ni] : cs0[ni];
        s += __shfl_xor(s, 16);
        s += __shfl_xor(s, 32);
        if (lane < 16) sums[((size_t)bh*NSC + sc0 + h2)*64 + ni*16 + fr] = s;
      }
    }
  }
  #undef STAGE_A
  #undef STAGE_B
  #undef BAR_IN
  #undef BAR_OUT
  #undef PHASE_MFMA
}

// ---------------- exclusive scan over scan-chunk axis (2 arrays, in place) ----------------
__global__ __launch_bounds__(64) void scan2_kernel(float* __restrict__ A, float* __restrict__ Bv){
  int bh = blockIdx.x, d = threadIdx.x;
  float ra = 0.f, rb = 0.f;
  for (int c = 0; c < NSC; c++){
    size_t o = ((size_t)bh * NSC + c) * 64 + d;
    float ta = A[o], tb = Bv[o];
    A[o] = ra; Bv[o] = rb;
    ra += ta; rb += tb;
  }
}

// ---------------- fused sink_incoming/source_outgoing + mod chunk sums ----------------
__global__ __launch_bounds__(64) void siso_fused_kernel(
    const u16* __restrict__ q, const u16* __restrict__ k,
    const float* __restrict__ sumQx, const float* __restrict__ sumKx,
    float* __restrict__ si, float* __restrict__ so,
    float* __restrict__ sumQsi, float* __restrict__ sumKso)
{
  __shared__ float cq[64*64];
  __shared__ float ck[64*64];
  __shared__ float siv[64], sov[64];
  int bhc = blockIdx.x; int bh = bhc >> 6, sc = bhc & 63;
  int b = bh >> 4, h = bh & 15;
  int lane = threadIdx.x;
  size_t gbase = ((size_t)(b*L_ + sc*SC))*DM + h*D_;
  size_t lb = (size_t)bh*L_ + sc*SC;
  {
    float runQ = sumQx[bhc*64 + lane];
    float runK = sumKx[bhc*64 + lane];
    for (int l = 0; l < SC; l++){
      runQ += bf2f(q[gbase + (size_t)l*DM + lane]);
      runK += bf2f(k[gbase + (size_t)l*DM + lane]);
      int sw = lane ^ (l & 31);
      cq[l*64 + sw] = runQ;
      ck[l*64 + sw] = runK;
    }
  }
  __syncthreads();
  {
    int l = lane;
    const u16* qrow = q + gbase + (size_t)l*DM;
    const u16* krow = k + gbase + (size_t)l*DM;
    uint4 qr[8], kr[8];
    #pragma unroll
    for (int j=0;j<8;j++){ qr[j]=((const uint4*)qrow)[j]; kr[j]=((const uint4*)krow)[j]; }
    const u16* qp = (const u16*)qr; const u16* kp = (const u16*)kr;
    float a = 0.f, b2 = 0.f;
    #pragma unroll
    for (int d = 0; d < 64; d++){
      int sw = d ^ (l & 31);
      a  += (bf2f(qp[d])+EPSF) * (ck[l*64+sw]+EPSF);
      b2 += (bf2f(kp[d])+EPSF) * (cq[l*64+sw]+EPSF);
    }
    float n = (float)(sc*SC + l + 1);
    float vsi = n/a, vso = n/b2;
    si[lb+l] = vsi; so[lb+l] = vso;
    siv[l] = vsi;   sov[l] = vso;
  }
  __syncthreads();
  {
    float sq = 0.f, sk = 0.f;
    for (int l = 0; l < SC; l++){
      sq += bf2f(q[gbase + (size_t)l*DM + lane]) * siv[l];
      sk += bf2f(k[gbase + (size_t)l*DM + lane]) * sov[l];
    }
    sumQsi[bhc*64 + lane] = sq;
    sumKso[bhc*64 + lane] = sk;
  }
}

// ---------------- fused conserved_sink/source -> sall, csrc + exp chunk sums ----------------
__global__ __launch_bounds__(64) void cons_fused_kernel(
    const u16* __restrict__ q, const u16* __restrict__ k,
    const float* __restrict__ si, const float* __restrict__ so,
    const float* __restrict__ sumQsiX, const float* __restrict__ sumKsoX,
    float* __restrict__ csrc, float* __restrict__ sall, float* __restrict__ csSum)
{
  __shared__ float cq[64*64];
  __shared__ float ck[64*64];
  __shared__ float siv[64], sov[64];
  int bhc = blockIdx.x; int bh = bhc >> 6, sc = bhc & 63;
  int b = bh >> 4, h = bh & 15;
  int lane = threadIdx.x;
  size_t gbase = ((size_t)(b*L_ + sc*SC))*DM + h*D_;
  size_t lb = (size_t)bh*L_ + sc*SC;
  siv[lane] = si[lb + lane];
  sov[lane] = so[lb + lane];
  __syncthreads();
  {
    float runQ = sumQsiX[bhc*64 + lane];
    float runK = sumKsoX[bhc*64 + lane];
    for (int l = 0; l < SC; l++){
      runQ += bf2f(q[gbase + (size_t)l*DM + lane]) * siv[l];
      runK += bf2f(k[gbase + (size_t)l*DM + lane]) * sov[l];
      int sw = lane ^ (l & 31);
      cq[l*64 + sw] = runQ;
      ck[l*64 + sw] = runK;
    }
  }
  __syncthreads();
  {
    int l = lane;
    const u16* qrow = q + gbase + (size_t)l*DM;
    const u16* krow = k + gbase + (size_t)l*DM;
    uint4 qr[8], kr[8];
    #pragma unroll
    for (int j=0;j<8;j++){ qr[j]=((const uint4*)qrow)[j]; kr[j]=((const uint4*)krow)[j]; }
    const u16* qp = (const u16*)qr; const u16* kp = (const u16*)kr;
    float a = 0.f, b2 = 0.f;
    #pragma unroll
    for (int d = 0; d < 64; d++){
      int sw = d ^ (l & 31);
      a  += (bf2f(qp[d])+EPSF) * (ck[l*64+sw]+EPSF);
      b2 += (bf2f(kp[d])+EPSF) * (cq[l*64+sw]+EPSF);
    }
    float inv = 1.0f / (float)(sc*SC + l + 1);
    sall[lb+l] = sigmoidf_(a * inv);
    float cs = b2 * inv;
    csrc[lb+l] = cs;
    float e = __expf(cs);
    #pragma unroll
    for (int off = 32; off > 0; off >>= 1) e += __shfl_xor(e, off);
    if (lane == 0) csSum[bhc] = e;
  }
}

// ---------------- exclusive scan of exp-chunk-sums over NSC chunks ----------------
__global__ __launch_bounds__(64) void cs_scan_kernel(const float* __restrict__ csSum, float* __restrict__ csOff){
  int bh = blockIdx.x; int lane = threadIdx.x;
  float v = csSum[bh * NSC + lane];
  float run = v;
  #pragma unroll
  for (int o = 1; o < 64; o <<= 1){
    float t = __shfl_up(run, o);
    if (lane >= o) run += t;
  }
  csOff[bh * NSC + lane] = run - v;  // exclusive
}

// ---------------- source_competition ----------------
__global__ __launch_bounds__(64) void scomp_kernel(
    const float* __restrict__ csrc, const float* __restrict__ csOff,
    float* __restrict__ scomp){
  int bhc = blockIdx.x; int bh = bhc >> 6, sc = bhc & 63;
  int lane = threadIdx.x;
  size_t idx = (size_t)bh * L_ + sc * SC + lane;
  float cs = __expf(csrc[idx]);
  float run = cs;
  #pragma unroll
  for (int o = 1; o < 64; o <<= 1){
    float t = __shfl_up(run, o);
    if (lane >= o) run += t;
  }
  scomp[idx] = cs / (csOff[bh*NSC + sc] + run) * (float)(sc*SC + lane + 1);
}

// ---------------- per-chunk VK sums: VK[m][d] = sum_l v[l][m]*scomp[l]*k[l][d] ----------------
__global__ __launch_bounds__(256) void vk_chunk_kernel(
    const u16* __restrict__ k, const u16* __restrict__ v,
    const float* __restrict__ scomp, float* __restrict__ vkc){
  __shared__ float ks[32][64];
  __shared__ float vs[32][64];
  int bhc = blockIdx.x; int bh = bhc >> 5, c = bhc & 31;
  int b = bh >> 4, h = bh & 15;
  int tid = threadIdx.x;
  int m = tid >> 2, d0 = (tid & 3) * 16;
  float acc[16];
  #pragma unroll
  for (int j = 0; j < 16; j++) acc[j] = 0.f;
  size_t gbase = ((size_t)(b * L_ + c * CS)) * DM + h * D_;
  size_t sbase = (size_t)bh * L_ + c * CS;
  int r = tid >> 3, cc = (tid & 7) * 8;
  for (int s0 = 0; s0 < CS; s0 += 32){
    __syncthreads();
    float sc = scomp[sbase + s0 + r];
    uint4 ku = *(const uint4*)(k + gbase + (size_t)(s0 + r) * DM + cc);
    uint4 vu = *(const uint4*)(v + gbase + (size_t)(s0 + r) * DM + cc);
    const u16* kp = (const u16*)&ku; const u16* vp = (const u16*)&vu;
    #pragma unroll
    for (int j = 0; j < 8; j++){
      ks[r][cc + j] = bf2f(kp[j]);
      vs[r][cc + j] = bf2f(vp[j]) * sc;
    }
    __syncthreads();
    #pragma unroll
    for (int i = 0; i < 32; i++){
      float vm = vs[i][m];
      #pragma unroll
      for (int j4 = 0; j4 < 4; j4++){
        float4 kk = *(const float4*)&ks[i][d0 + j4*4];
        acc[j4*4+0] += vm * kk.x; acc[j4*4+1] += vm * kk.y;
        acc[j4*4+2] += vm * kk.z; acc[j4*4+3] += vm * kk.w;
      }
    }
  }
  float* outp = vkc + (size_t)bhc * (D_*D_) + m * D_ + d0;
  #pragma unroll
  for (int j = 0; j < 16; j++) outp[j] = acc[j];
}

// ---------------- exclusive scan of VK over chunks (in place) ----------------
__global__ __launch_bounds__(256) void vk_scan_kernel(float* __restrict__ vkc){
  int idx = blockIdx.x * 256 + threadIdx.x;   // over BH*4096
  int bh = idx >> 12;
  int e  = idx & 4095;
  size_t base = ((size_t)bh * NC) * 4096 + e;
  float run = 0.f;
  for (int c = 0; c < NC; c++){
    size_t o = base + (size_t)c * 4096;
    float t = vkc[o]; vkc[o] = run; run += t;
  }
}

// ---------------- causal attention per (bh, chunk) ----------------
__global__ __launch_bounds__(256) void attn_kernel(
    const u16* __restrict__ q, const u16* __restrict__ k, const u16* __restrict__ v,
    const float* __restrict__ si, const float* __restrict__ scomp, const float* __restrict__ salloc,
    const float* __restrict__ vkc, u16* __restrict__ attnout)
{
  __shared__ __align__(16) u16 qs[128*64];    // qmod rows [l][d]
  __shared__ __align__(16) u16 ks2[128*64];   // k rows    [j][d]
  __shared__ __align__(16) u16 vts[64*128];   // (v*scomp)^T [m][j]
  __shared__ __align__(16) u16 vks[64*64];    // VKprev [m][d]
  __shared__ __align__(16) u16 ss[128*32];    // masked S strip [l][j-in-32]
  int bhc = blockIdx.x; int bh = bhc >> 5, c = bhc & 31;
  int b = bh >> 4, h = bh & 15;
  int tid = threadIdx.x, wave = tid >> 6, lane = tid & 63;
  size_t gbase = ((size_t)(b * L_ + c * CS)) * DM + h * D_;
  size_t sbase = (size_t)bh * L_ + c * CS;
  {
    int r = tid >> 1;
    int cc = (tid & 1) * 32;
    int l = c * CS + r;
    float qscale = si[sbase + r] / (float)(l + 1);
    float vscale = scomp[sbase + r];
    #pragma unroll
    for (int j = 0; j < 4; j++){
      uint4 qu = *(const uint4*)(q + gbase + (size_t)r * DM + cc + j*8);
      uint4 kuv = *(const uint4*)(k + gbase + (size_t)r * DM + cc + j*8);
      uint4 vu = *(const uint4*)(v + gbase + (size_t)r * DM + cc + j*8);
      const u16* qp = (const u16*)&qu; const u16* vp = (const u16*)&vu;
      u16 tmp[8];
      #pragma unroll
      for (int e = 0; e < 8; e++) tmp[e] = f2bf(bf2f(qp[e]) * qscale);
      *(uint4*)&qs[r*64 + cc + j*8] = *(uint4*)tmp;
      *(uint4*)&ks2[r*64 + cc + j*8] = kuv;
      #pragma unroll
      for (int e = 0; e < 8; e++) vts[(cc + j*8 + e)*128 + r] = f2bf(bf2f(vp[e]) * vscale);
    }
    const float* vkp = vkc + (size_t)bhc * (D_*D_) + tid * 16;
    u16 tv[16];
    #pragma unroll
    for (int e = 0; e < 16; e++) tv[e] = f2bf(vkp[e]);
    *(uint4*)&vks[tid*16]   = *(uint4*)&tv[0];
    *(uint4*)&vks[tid*16+8] = *(uint4*)&tv[8];
  }
  __syncthreads();
  int t0 = wave, t1 = 7 - wave;   // balanced l-tile pair per wave
  int fr = lane & 15, kg = (lane >> 4) * 8;
  f32x4 acc[2][4];
  #pragma unroll
  for (int i=0;i<2;i++)
    #pragma unroll
    for (int j=0;j<4;j++) acc[i][j] = (f32x4){0.f,0.f,0.f,0.f};
  s16x8 aq[2][2];
  #pragma unroll
  for (int ti = 0; ti < 2; ti++){
    int t = ti ? t1 : t0;
    #pragma unroll
    for (int kk = 0; kk < 2; kk++)
      aq[ti][kk] = *(const s16x8*)&qs[(t*16 + fr)*64 + kk*32 + kg];
  }
  #pragma unroll
  for (int mt = 0; mt < 4; mt++){
    #pragma unroll
    for (int kk = 0; kk < 2; kk++){
      s16x8 bv = *(const s16x8*)&vks[(mt*16 + fr)*64 + kk*32 + kg];
      acc[0][mt] = mfma16(aq[0][kk], bv, acc[0][mt]);
      acc[1][mt] = mfma16(aq[1][kk], bv, acc[1][mt]);
    }
  }
  for (int jt = 0; jt < 4; jt++){
    __syncthreads();
    #pragma unroll
    for (int ti = 0; ti < 2; ti++){
      int t = ti ? t1 : t0;
      #pragma unroll
      for (int u = 0; u < 2; u++){
        int jj = jt*2 + u;
        f32x4 sacc = (f32x4){0.f,0.f,0.f,0.f};
        if (jj <= t){
          #pragma unroll
          for (int kk = 0; kk < 2; kk++){
            s16x8 bkf = *(const s16x8*)&ks2[(jj*16 + fr)*64 + kk*32 + kg];
            sacc = mfma16(aq[ti][kk], bkf, sacc);
          }
        }
        int lrow = t*16 + (lane>>4)*4;
        int jcol = jj*16 + fr;
        #pragma unroll
        for (int r = 0; r < 4; r++){
          float sv = (jcol <= lrow + r) ? sacc[r] : 0.f;
          ss[(lrow + r)*32 + u*16 + fr] = f2bf(sv);
        }
      }
    }
    __syncthreads();
    #pragma unroll
    for (int ti = 0; ti < 2; ti++){
      int t = ti ? t1 : t0;
      if (jt*32 <= t*16 + 15){
        s16x8 as = *(const s16x8*)&ss[(t*16 + fr)*32 + kg];
        #pragma unroll
        for (int mt = 0; mt < 4; mt++){
          s16x8 bvv = *(const s16x8*)&vts[(mt*16 + fr)*128 + jt*32 + kg];
          acc[ti][mt] = mfma16(as, bvv, acc[ti][mt]);
        }
      }
    }
  }
  #pragma unroll
  for (int ti = 0; ti < 2; ti++){
    int t = ti ? t1 : t0;
    int lrow = t*16 + (lane>>4)*4;
    #pragma unroll
    for (int r = 0; r < 4; r++){
      float sa = salloc[sbase + lrow + r];
      size_t orow = ((size_t)(b * L_ + c * CS + lrow + r)) * DM + h * D_;
      #pragma unroll
      for (int mt = 0; mt < 4; mt++){
        attnout[orow + mt*16 + fr] = f2bf(acc[ti][mt][r] * sa);
      }
    }
  }
}

extern "C" void kernel_launch(void* const* d_in, const int* in_sizes, int n_in,
                              void* d_out, int out_size, void* d_ws, size_t ws_size,
                              hipStream_t stream){
  (void)in_sizes; (void)n_in; (void)out_size; (void)ws_size;
  const float* x  = (const float*)d_in[0];
  const float* Wq = (const float*)d_in[1];
  const float* bq = (const float*)d_in[2];
  const float* Wk = (const float*)d_in[3];
  const float* bk = (const float*)d_in[4];
  const float* Wv = (const float*)d_in[5];
  const float* bv = (const float*)d_in[6];
  const float* Wo = (const float*)d_in[7];
  const float* bo = (const float*)d_in[8];

  char* p = (char*)d_ws;
  auto carve = [&](size_t bytes) -> void* {
    void* r = (void*)p; p += (bytes + 255) & ~(size_t)255; return r;
  };
  u16* xb    = (u16*)carve((size_t)N_*DM*2);
  u16* wqkvT = (u16*)carve((size_t)3*DM*DM*2);
  u16* woT   = (u16*)carve((size_t)DM*DM*2);
  u16* qb  = (u16*)carve((size_t)N_*DM*2);
  u16* kb  = (u16*)carve((size_t)N_*DM*2);
  u16* vb  = (u16*)carve((size_t)N_*DM*2);
  u16* ao  = (u16*)carve((size_t)N_*DM*2);
  float* si   = (float*)carve((size_t)BH*L_*4);
  float* so   = (float*)carve((size_t)BH*L_*4);
  float* csrc = (float*)carve((size_t)BH*L_*4);
  float* sall = (float*)carve((size_t)BH*L_*4);
  float* scmp = (float*)carve((size_t)BH*L_*4);
  float* sumQ   = (float*)carve((size_t)BH*NSC*D_*4);
  float* sumK   = (float*)carve((size_t)BH*NSC*D_*4);
  float* sumQsi = (float*)carve((size_t)BH*NSC*D_*4);
  float* sumKso = (float*)carve((size_t)BH*NSC*D_*4);
  float* csSum  = (float*)carve((size_t)BH*NSC*4);
  float* csOff  = (float*)carve((size_t)BH*NSC*4);
  float* vkc    = (float*)carve((size_t)BH*NC*(size_t)(D_*D_)*4);

  // 1. conversions
  cvt_kernel<<<(N_*DM/4 + 255)/256, 256, 0, stream>>>(x, xb, N_*DM/4);
  transpose_w4_kernel<<<dim3(DM/64, DM/64, 4), 256, 0, stream>>>(Wq, Wk, Wv, Wo, wqkvT, woT);
  // 2. fused q,k,v projection (one 16384x3072x1024 GEMM) + per-scan-chunk sums
  gemm256_kernel<1><<<dim3((N_/256)*(3*DM/256)), 512, 0, stream>>>(
      xb, wqkvT, bq, bk, bv, qb, kb, vb, nullptr, sumQ, sumK, 3*DM/256);
  // 3. normalizer pipeline
  scan2_kernel<<<BH, 64, 0, stream>>>(sumQ, sumK);
  siso_fused_kernel<<<BH*NSC, 64, 0, stream>>>(qb, kb, sumQ, sumK, si, so, sumQsi, sumKso);
  scan2_kernel<<<BH, 64, 0, stream>>>(sumQsi, sumKso);
  cons_fused_kernel<<<BH*NSC, 64, 0, stream>>>(qb, kb, si, so, sumQsi, sumKso, csrc, sall, csSum);
  cs_scan_kernel<<<BH, 64, 0, stream>>>(csSum, csOff);
  scomp_kernel<<<BH*NSC, 64, 0, stream>>>(csrc, csOff, scmp);
  // 4. causal linear attention
  vk_chunk_kernel<<<BH*NC, 256, 0, stream>>>(kb, vb, scmp, vkc);
  vk_scan_kernel<<<(BH*D_*D_)/256, 256, 0, stream>>>(vkc);
  attn_kernel<<<BH*NC, 256, 0, stream>>>(qb, kb, vb, si, scmp, sall, vkc, ao);
  // 5. output projection
  gemm256_kernel<0><<<dim3((N_/256)*(DM/256)), 512, 0, stream>>>(
      ao, woT, bo, bo, bo, nullptr, nullptr, nullptr, (float*)d_out, nullptr, nullptr, DM/256);
}